// Round 5
// baseline (2452.858 us; speedup 1.0000x reference)
//
#include <hip/hip_runtime.h>

typedef unsigned short u16;
typedef __attribute__((ext_vector_type(8))) short short8;
typedef __attribute__((ext_vector_type(4))) float f32x4;

#define BN_ 64
#define CN_ 32
#define WN_ 40
#define RN_ 36
#define DN_ 1024
#define SN_ 256
#define KN_ 5
#define EPS_ 1e-8f
#define BNE_ 1e-5f
#define LNE_ 1e-5f
#define SMOOTH_ 9.0f

__device__ __forceinline__ float bf2f(u16 u){ return __uint_as_float(((unsigned)u)<<16); }
__device__ __forceinline__ u16 f2bf(float f){
  unsigned u = __float_as_uint(f);
  u += 0x7fffu + ((u>>16)&1u);
  return (u16)(u>>16);
}
// mode=1: tensor memory is float32. mode=0: bf16 (confirmed mode==0 on this harness)
__device__ __forceinline__ float ldf(const void* p, size_t i, int mode){
  return mode ? ((const float*)p)[i] : bf2f(((const u16*)p)[i]);
}
__device__ __forceinline__ void stf(void* p, size_t i, float v, int mode){
  if (mode) ((float*)p)[i] = v; else ((u16*)p)[i] = f2bf(v);
}
__device__ __forceinline__ int get_mode(const unsigned* oneflag){
  return (oneflag[0] == 0x3F800000u) ? 1 : 0;   // ln_g[0]==1.0f as f32
}
// load 8 consecutive elements as a bf16 fragment (16B vector load in mode 0)
__device__ __forceinline__ short8 ld_frag8(const void* p, size_t elem, int mode){
  if (mode == 0){
    union { uint4 u; short8 s; } cv;
    cv.u = *(const uint4*)((const u16*)p + elem);
    return cv.s;
  } else {
    const float* f = (const float*)p;
    short8 r;
#pragma unroll
    for (int j=0;j<8;j++) r[j] = (short)f2bf(f[elem+j]);
    return r;
  }
}

__device__ __forceinline__ float wave_sum(float v){
#pragma unroll
  for (int off=32; off>0; off>>=1) v += __shfl_down(v, off, 64);
  return v;
}
// blockDim.x == 256
__device__ float block_sum(float v, float* sc4){
  v = wave_sum(v);
  if ((threadIdx.x & 63)==0) sc4[threadIdx.x>>6] = v;
  __syncthreads();
  float r = sc4[0]+sc4[1]+sc4[2]+sc4[3];
  __syncthreads();
  return r;
}

// ---------------- mean over middle axis
__global__ void mean_k(const void* X, float* out, int G, int L, float inv, const unsigned* oneflag){
  int mode = get_mode(oneflag);
  int idx = blockIdx.x*256 + threadIdx.x;
  if (idx >= G*DN_) return;
  int g = idx >> 10, d = idx & 1023;
  size_t base = (size_t)g*L*DN_ + d;
  float s = 0.f;
  for (int l=0; l<L; l++) s += ldf(X, base + (size_t)l*DN_, mode);
  out[idx] = s*inv;
}

// ---------------- retile weight W (K=1024 rows, N cols, k-major) -> WT[kt][n][64] bf16
__global__ void prep_w_k(const void* W, u16* WT, int nlog2, const unsigned* oneflag){
  int mode = get_mode(oneflag);
  int N = 1 << nlog2;
  int idx = blockIdx.x*256 + threadIdx.x;
  if (idx >= (DN_<<nlog2)) return;
  int k = idx >> nlog2, n = idx & (N-1);
  float v = ldf(W, idx, mode);
  WT[(((size_t)(k>>6))*N + n)*64 + (k&63)] = f2bf(v);
}

// ================= generic MFMA NT-GEMM =================
// C[M,N] f32 = act(A @ B + bias). A: M×K row-major (input dtype).
// B: if bt==1, N×K row-major (input dtype); else WT-tiled [kt][N][64] bf16.
// Zero LDS, zero barriers: all fragments 16B direct loads (L1/L2).
// tile 64(M)×64(N); wave w owns 16 n.
__global__ __launch_bounds__(256) void gemm_nt_mfma_k(
    const void* A, const void* B, int bt, const u16* WT,
    const void* bias, int has_bias, int act, const unsigned* oneflag,
    float* C, int M, int N, int K){
  int mode = get_mode(oneflag);
  int t = threadIdx.x;
  int w = t>>6, lane = t&63, q = lane>>4, cm = lane&15;
  int m0 = blockIdx.y*64, n0 = blockIdx.x*64 + w*16;
  f32x4 acc[4];
#pragma unroll
  for (int mt=0;mt<4;mt++) acc[mt] = (f32x4){0.f,0.f,0.f,0.f};
  int nkt = K>>6;
  for (int kt=0; kt<nkt; kt++){
#pragma unroll
    for (int ks=0; ks<2; ks++){
      int kb = kt*64 + ks*32 + q*8;
      short8 b;
      if (bt) b = ld_frag8(B, (size_t)(n0+cm)*K + kb, mode);
      else {
        union { uint4 u; short8 s; } cv;
        cv.u = *(const uint4*)(WT + (((size_t)kt*N + n0+cm)*64 + ks*32 + q*8));
        b = cv.s;
      }
#pragma unroll
      for (int mt=0; mt<4; mt++){
        short8 a = ld_frag8(A, (size_t)(m0+mt*16+cm)*K + kb, mode);
        acc[mt] = __builtin_amdgcn_mfma_f32_16x16x32_bf16(a, b, acc[mt], 0,0,0);
      }
    }
  }
  float bv = has_bias ? ldf(bias, n0+cm, mode) : 0.f;
#pragma unroll
  for (int mt=0; mt<4; mt++){
#pragma unroll
    for (int r=0; r<4; r++){
      int m = m0 + mt*16 + q*4 + r;
      float v = acc[mt][r] + bv;
      if (act==1) v = tanhf(v);
      C[(size_t)m*N + n0+cm] = v;
    }
  }
}

// ---------------- BN-local split
__global__ void bnl_sum_k(const float* h, float* bnp){
  __shared__ float sc[4];
  int r = blockIdx.x>>3, bg = blockIdx.x&7;
  float s=0.f, s2=0.f;
  for (int bb=0; bb<8; bb++){
    int b = bg*8+bb;
    const float* p = h + ((size_t)b*RN_ + r)*DN_;
    for (int d=threadIdx.x; d<DN_; d+=256){ float x=p[d]; s+=x; s2+=x*x; }
  }
  s  = block_sum(s,  sc);
  s2 = block_sum(s2, sc);
  if (threadIdx.x==0){ bnp[blockIdx.x*2]=s; bnp[blockIdx.x*2+1]=s2; }
}
__global__ void bnl_apply_k(float* h, const void* gg_, const void* bb_,
                            const float* bnp, const unsigned* oneflag){
  int mode = get_mode(oneflag);
  int row = blockIdx.x; int r = row % RN_;
  float s=0.f, s2=0.f;
  for (int j=0;j<8;j++){ s += bnp[(r*8+j)*2]; s2 += bnp[(r*8+j)*2+1]; }
  float inv = 1.f/(float)(BN_*DN_);
  float mu = s*inv;
  float var = s2*inv - mu*mu;
  float rstd = rsqrtf(var + BNE_);
  float gg = ldf(gg_, r, mode), bb = ldf(bb_, r, mode);
  float* p = h + (size_t)row*DN_;
  for (int d=threadIdx.x; d<DN_; d+=256) p[d] = tanhf((p[d]-mu)*rstd*gg + bb);
}

// ---------------- BN over batch per feature + tanh
__global__ void bn_global_k(float* g, const void* gg_, const void* bb_, const unsigned* oneflag){
  int mode = get_mode(oneflag);
  int d = blockIdx.x*256 + threadIdx.x;
  if (d >= DN_) return;
  float s=0.f, s2=0.f;
  for (int b=0;b<BN_;b++){ float x=g[(size_t)b*DN_+d]; s+=x; s2+=x*x; }
  float m = s/(float)BN_;
  float var = s2/(float)BN_ - m*m;
  float rstd = rsqrtf(var + BNE_);
  float ga=ldf(gg_,d,mode), be=ldf(bb_,d,mode);
  for (int b=0;b<BN_;b++){
    size_t i=(size_t)b*DN_+d;
    g[i] = tanhf((g[i]-m)*rstd*ga + be);
  }
}

// ---------------- VALU tiled GEMM (kept for the two tiny f32-A GEMMs)
__global__ void gemm_k(const void* A, int a_ws, const void* B, int transb,
                       const void* bias, int has_bias, int act,
                       const unsigned* oneflag, float* C, int M, int N, int K){
  __shared__ float As[32][33];
  __shared__ float Bs[32][33];
  int mode = get_mode(oneflag);
  int n0 = blockIdx.x*32, m0 = blockIdx.y*32;
  int tid = threadIdx.x;
  int tx = tid & 15, ty = tid >> 4;
  float a00=0,a01=0,a10=0,a11=0;
  for (int kt=0; kt<K; kt+=32){
    for (int l=0; l<4; l++){
      int idx = tid + l*256;
      {
        int i = idx >> 5, k = idx & 31;
        int m = m0 + i;
        float v = 0.f;
        if (m < M){
          size_t off = (size_t)m*K + kt + k;
          v = a_ws ? ((const float*)A)[off] : ldf(A, off, mode);
        }
        As[i][k] = v;
      }
      if (!transb){
        int k = idx >> 5, j = idx & 31;
        int n = n0 + j;
        Bs[k][j] = (n<N) ? ldf(B, (size_t)(kt+k)*N + n, mode) : 0.f;
      } else {
        int j = idx >> 5, k = idx & 31;
        int n = n0 + j;
        Bs[k][j] = (n<N) ? ldf(B, (size_t)n*K + kt + k, mode) : 0.f;
      }
    }
    __syncthreads();
#pragma unroll
    for (int kk=0; kk<32; kk++){
      float x0 = As[ty][kk], x1 = As[ty+16][kk];
      float y0 = Bs[kk][tx], y1 = Bs[kk][tx+16];
      a00 += x0*y0; a01 += x0*y1; a10 += x1*y0; a11 += x1*y1;
    }
    __syncthreads();
  }
  float acc[2][2] = {{a00,a01},{a10,a11}};
  for (int i=0;i<2;i++){
    for (int j=0;j<2;j++){
      int m = m0 + ty + i*16, n = n0 + tx + j*16;
      if (m<M && n<N){
        float v = acc[i][j];
        if (has_bias) v += ldf(bias, n, mode);
        if (act==1) v = tanhf(v);
        C[(size_t)m*N + n] = v;
      }
    }
  }
}

// ---------------- weights_raw[b,r]
__global__ void wraw_k(const float* lemb, const float* gemb, const void* vc_w, const void* vc_b,
                       float* wraw, const unsigned* oneflag){
  __shared__ float sc[4];
  int mode = get_mode(oneflag);
  int br = blockIdx.x; int b = br / RN_;
  const float* lp = lemb + (size_t)br*DN_;
  const float* gp = gemb + (size_t)b*DN_;
  float s=0.f;
  for (int d=threadIdx.x; d<DN_; d+=256) s += lp[d]*gp[d]*ldf(vc_w,d,mode);
  s = block_sum(s, sc);
  if (threadIdx.x==0) wraw[br] = s + ldf(vc_b,0,mode);
}

// ---------------- region softmax -> weighted sum -> l2norm
__global__ void glo_k(const float* wraw, const void* img, float* img_glo, float* rnorm,
                      const unsigned* oneflag){
  __shared__ float sc[4];
  __shared__ float wsm[RN_];
  __shared__ float srn;
  int mode = get_mode(oneflag);
  int b = blockIdx.x;
  if (threadIdx.x==0){
    float mx=-1e30f;
    for (int r=0;r<RN_;r++) mx = fmaxf(mx, wraw[b*RN_+r]);
    float sum=0.f;
    for (int r=0;r<RN_;r++){ float e=expf(wraw[b*RN_+r]-mx); wsm[r]=e; sum+=e; }
    float inv=1.f/sum;
    for (int r=0;r<RN_;r++) wsm[r]*=inv;
  }
  __syncthreads();
  float ng[4]; float s2=0.f;
#pragma unroll
  for (int j=0;j<4;j++){
    int d = threadIdx.x + j*256;
    float s=0.f;
    for (int r=0;r<RN_;r++) s += wsm[r]*ldf(img, ((size_t)b*RN_+r)*DN_ + d, mode);
    ng[j]=s; s2 += s*s;
  }
  s2 = block_sum(s2, sc);
  if (threadIdx.x==0) srn = 1.f/(sqrtf(s2)+EPS_);
  __syncthreads();
  float rn = srn;
#pragma unroll
  for (int j=0;j<4;j++) img_glo[(size_t)b*DN_ + threadIdx.x + j*256] = ng[j]*rn;
  if (threadIdx.x==0) rnorm[b]=rn;
}

// ---------------- partial embeddings (output bf16)
__global__ void partial_k(const float* wraw, const int* adjs, const void* img,
                          const float* rnorm, u16* img_parh, const unsigned* oneflag){
  __shared__ float wg[KN_];
  __shared__ int eff[KN_];
  int mode = get_mode(oneflag);
  int br = blockIdx.x; int b = br / RN_; int r = br % RN_;
  if (threadIdx.x==0){
    int cnt=0;
    const int* ap = adjs + (size_t)br*RN_;
    for (int j=0;j<RN_ && cnt<KN_;j++) if (ap[j]==1) eff[cnt++]=j;
    for (int k=cnt;k<KN_;k++) eff[k]=r;
    float v[KN_]; float mx=-1e30f;
    for (int k=0;k<KN_;k++){ v[k]=wraw[b*RN_+eff[k]]; mx=fmaxf(mx,v[k]); }
    float sum=0.f;
    for (int k=0;k<KN_;k++){ v[k]=expf(v[k]-mx); sum+=v[k]; }
    float inv=1.f/sum;
    for (int k=0;k<KN_;k++) wg[k]=v[k]*inv;
  }
  __syncthreads();
  float rn = rnorm[b];
  for (int d=threadIdx.x; d<DN_; d+=256){
    float s=0.f;
#pragma unroll
    for (int k=0;k<KN_;k++) s += wg[k]*ldf(img, ((size_t)b*RN_+eff[k])*DN_ + d, mode);
    img_parh[(size_t)br*DN_ + d] = f2bf(s*rn);
  }
}

// ---------------- caption attention pool -> cap_glo
__global__ void capglo_k(const float* le, const float* ge, const void* tsa_cw, const void* tsa_cb,
                         const void* cap, float* cap_glo, const unsigned* oneflag){
  __shared__ float sc[4];
  __shared__ float score[WN_];
  __shared__ float srn;
  int mode = get_mode(oneflag);
  int c = blockIdx.x;
  int t = threadIdx.x;
  float gw[4];
#pragma unroll
  for (int j=0;j<4;j++){ int d=t+j*256; gw[j] = ge[(size_t)c*DN_+d]*ldf(tsa_cw,d,mode); }
  float cb0 = ldf(tsa_cb,0,mode);
  for (int n=0;n<WN_;n++){
    const float* lp = le + ((size_t)c*WN_+n)*DN_;
    float s=0.f;
#pragma unroll
    for (int j=0;j<4;j++) s += lp[t+j*256]*gw[j];
    s = block_sum(s, sc);
    if (t==0) score[n] = s + cb0;
  }
  __syncthreads();
  if (t==0){
    float mx=-1e30f;
    for (int n=0;n<WN_;n++) mx=fmaxf(mx,score[n]);
    float sum=0.f;
    for (int n=0;n<WN_;n++){ float e=expf(score[n]-mx); score[n]=e; sum+=e; }
    float inv=1.f/sum;
    for (int n=0;n<WN_;n++) score[n]*=inv;
  }
  __syncthreads();
  float v[4]; float s2=0.f;
#pragma unroll
  for (int j=0;j<4;j++){
    int d=t+j*256;
    float s=0.f;
    for (int n=0;n<WN_;n++) s += score[n]*ldf(cap, ((size_t)c*WN_+n)*DN_ + d, mode);
    v[j]=s; s2+=s*s;
  }
  s2 = block_sum(s2, sc);
  if (t==0) srn = 1.f/(sqrtf(s2)+EPS_);
  __syncthreads();
#pragma unroll
  for (int j=0;j<4;j++) cap_glo[(size_t)c*DN_ + t + j*256] = v[j]*srn;
}

// ---------------- leaky_relu + l2norm over regions, in place
__global__ void attn_norm_k(float* attn){
  int idx = blockIdx.x*256 + threadIdx.x;
  if (idx >= CN_*WN_*BN_) return;
  int cn = idx >> 6, b = idx & 63;
  float* p = attn + (size_t)cn*(BN_*RN_) + (size_t)b*RN_;
  float v[RN_]; float s2=0.f;
#pragma unroll
  for (int r=0;r<RN_;r++){ float x=p[r]; x = (x>=0.f)? x : 0.1f*x; v[r]=x; s2+=x*x; }
  float rn = 1.f/(sqrtf(s2)+EPS_);
#pragma unroll
  for (int r=0;r<RN_;r++) p[r]=v[r]*rn;
}

// ---------------- per-caption Gram
__global__ void gram_k(const void* cap, float* gram, const unsigned* oneflag){
  __shared__ float capS[WN_][128];
  int mode = get_mode(oneflag);
  int c = blockIdx.x, t = threadIdx.x;
  float acc[7];
  int pi[7], pj[7];
#pragma unroll
  for (int u=0; u<7; u++){
    acc[u]=0.f;
    int p = t + u*256;
    pi[u] = p/40; pj[u] = p%40;
    if (pi[u] >= WN_) pi[u] = 0;
  }
  for (int k0=0; k0<DN_; k0+=128){
    for (int i=t; i<WN_*128; i+=256){
      int n = i>>7, kk = i&127;
      capS[n][kk] = ldf(cap, ((size_t)c*WN_+n)*DN_ + k0+kk, mode);
    }
    __syncthreads();
#pragma unroll
    for (int u=0; u<7; u++){
      if (t + u*256 < 1600){
        float s=0.f;
        for (int kk=0; kk<128; kk++) s += capS[pi[u]][kk]*capS[pj[u]][kk];
        acc[u] += s;
      }
    }
    __syncthreads();
  }
#pragma unroll
  for (int u=0; u<7; u++)
    if (t + u*256 < 1600) gram[(size_t)c*1600 + t + u*256] = acc[u];
}

// ---------------- sim_glo
__global__ void simglo_k(const float* img_glo, const float* cap_glo, const void* glo_w,
                         const void* glo_b, float* simglo_ws, void* out, const unsigned* oneflag){
  __shared__ float X[DN_];
  __shared__ float sc[4];
  __shared__ float srn;
  int mode = get_mode(oneflag);
  int cb = blockIdx.x; int c = cb >> 6; int b = cb & 63;
  int t = threadIdx.x;
#pragma unroll
  for (int j=0;j<4;j++){
    int d=t+j*256;
    float dif = img_glo[(size_t)b*DN_+d] - cap_glo[(size_t)c*DN_+d];
    X[d] = dif*dif;
  }
  __syncthreads();
  float acc=0.f;
  for (int k=0;k<DN_;k++) acc += X[k]*ldf(glo_w, (size_t)k*SN_ + t, mode);
  acc += ldf(glo_b, t, mode);
  acc = fmaxf(acc, 0.f);
  float s2 = block_sum(acc*acc, sc);
  if (t==0) srn = 1.f/(sqrtf(s2)+EPS_);
  __syncthreads();
  float o = acc*srn;
  simglo_ws[(size_t)cb*SN_ + t] = o;
  stf(out, (size_t)cb*37*SN_ + t, o, mode);
  stf(out, (size_t)CN_*BN_*37*SN_ + (size_t)cb*SN_ + t, o, mode);
}

// ================= head GEMMs: M=64, N=256, frag-linear LDS, ping-pong, 1 barrier/kt ======

// ---- fused sim_par -> wts_raw
__global__ __launch_bounds__(256) void wts_mfma_k(const u16* img_parh, const float* cap_glo,
    const u16* WT, const void* par_b, const float* simglo, const void* sim_w,
    const void* sim_b, float* wts_raw, const unsigned* oneflag){
  __shared__ uint4 AsV[2][512];
  __shared__ float red[4][64];
  __shared__ float rns[64];
  int mode = get_mode(oneflag);
  int t = threadIdx.x;
  int rows0 = blockIdx.x*64;
  int c = rows0 / (BN_*RN_);
  int br0 = rows0 % (BN_*RN_);
  int w = t>>6, lane = t&63, q = lane>>4, cm = lane&15;
  f32x4 acc[4][4];
#pragma unroll
  for (int mt=0;mt<4;mt++)
#pragma unroll
    for (int nt=0;nt<4;nt++) acc[mt][nt] = (f32x4){0.f,0.f,0.f,0.f};

  for (int kt=0; kt<16; kt++){
    int p = kt&1;
#pragma unroll
    for (int h=0; h<2; h++){
      int fi = t + h*256;
      int mt = fi>>7, ks=(fi>>6)&1, ln=fi&63;
      int fq = ln>>4, fcm = ln&15;
      int row = mt*16+fcm;
      int kb = kt*64 + ks*32 + fq*8;
      union { uint4 u; u16 s[8]; } pv;
      pv.u = *(const uint4*)(img_parh + (size_t)(br0+row)*DN_ + kb);
      const float* cg = cap_glo + (size_t)c*DN_ + kb;
      union { uint4 u; u16 s[8]; } xs;
#pragma unroll
      for (int j=0;j<8;j++){ float d = bf2f(pv.s[j]) - cg[j]; xs.s[j] = f2bf(d*d); }
      AsV[p][fi & 511] = xs.u;
    }
    __syncthreads();
#pragma unroll
    for (int ks=0; ks<2; ks++){
      short8 a[4];
#pragma unroll
      for (int mt=0; mt<4; mt++){
        union { uint4 u; short8 s; } cv;
        cv.u = AsV[p][(mt*2+ks)*64 + lane];
        a[mt] = cv.s;
      }
#pragma unroll
      for (int nt=0; nt<4; nt++){
        int n = w*64 + nt*16 + cm;
        union { uint4 u; short8 s; } bv;
        bv.u = *(const uint4*)(WT + (((size_t)kt*SN_ + n)*64 + ks*32 + q*8));
#pragma unroll
        for (int mt=0; mt<4; mt++)
          acc[mt][nt] = __builtin_amdgcn_mfma_f32_16x16x32_bf16(a[mt], bv.s, acc[mt][nt], 0,0,0);
      }
    }
  }
  // bias + relu
  int sarr[4]; float sw[4];
#pragma unroll
  for (int nt=0; nt<4; nt++){
    int s = w*64+nt*16+cm;
    sarr[nt] = s;
    float pb = ldf(par_b, s, mode);
    sw[nt] = ldf(sim_w, s, mode);
#pragma unroll
    for (int mt=0;mt<4;mt++)
#pragma unroll
      for (int r=0;r<4;r++) acc[mt][nt][r] = fmaxf(acc[mt][nt][r]+pb, 0.f);
  }
  // per-row sumsq -> rns
#pragma unroll
  for (int mt=0;mt<4;mt++)
#pragma unroll
  for (int r=0;r<4;r++){
    float v=0.f;
#pragma unroll
    for (int nt=0;nt<4;nt++) v += acc[mt][nt][r]*acc[mt][nt][r];
    v += __shfl_xor(v,1,64); v += __shfl_xor(v,2,64);
    v += __shfl_xor(v,4,64); v += __shfl_xor(v,8,64);
    if (cm==0) red[w][mt*16+q*4+r] = v;
  }
  __syncthreads();
  if (t<64) rns[t] = 1.f/(sqrtf(red[0][t]+red[1][t]+red[2][t]+red[3][t])+EPS_);
  __syncthreads();
  // dot with simglo * sim_w
#pragma unroll
  for (int mt=0;mt<4;mt++)
#pragma unroll
  for (int r=0;r<4;r++){
    int rowl = mt*16+q*4+r;
    int br = br0+rowl; int b = br/RN_; int cb = c*BN_+b;
    float v=0.f;
#pragma unroll
    for (int nt=0;nt<4;nt++) v += acc[mt][nt][r]*simglo[(size_t)cb*SN_+sarr[nt]]*sw[nt];
    v += __shfl_xor(v,1,64); v += __shfl_xor(v,2,64);
    v += __shfl_xor(v,4,64); v += __shfl_xor(v,8,64);
    if (cm==0) red[w][rowl] = v;
  }
  __syncthreads();
  if (t<64) wts_raw[rows0+t] = (red[0][t]+red[1][t]+red[2][t]+red[3][t])*rns[t] + ldf(sim_b,0,mode);
}

// ---------------- LN over regions + sigmoid
__global__ void ln_k(const float* wts_raw, const void* ln_g, const void* ln_b,
                     float* wts_f, const unsigned* oneflag){
  int mode = get_mode(oneflag);
  int cb = blockIdx.x*256 + threadIdx.x;
  if (cb >= CN_*BN_) return;
  const float* p = wts_raw + (size_t)cb*RN_;
  float s=0.f, s2=0.f;
#pragma unroll
  for (int r=0;r<RN_;r++){ float x=p[r]; s+=x; s2+=x*x; }
  float m = s/(float)RN_;
  float v = s2/(float)RN_ - m*m;
  float rstd = rsqrtf(v + LNE_);
  float* q = wts_f + (size_t)cb*RN_;
#pragma unroll
  for (int r=0;r<RN_;r++){
    float x = (p[r]-m)*rstd*ldf(ln_g,r,mode) + ldf(ln_b,r,mode);
    q[r] = 1.f/(1.f+expf(-x));
  }
}

// ---- fused word-softmax -> ctx (Gram-normed) -> sim_loc -> *wts -> out
__global__ __launch_bounds__(256) void simloc_mfma_k(const float* attnr, const void* cap,
    const void* img, const u16* WT, const void* loc_b, const float* wts_f,
    const float* gram, void* out, const unsigned* oneflag){
  __shared__ uint4 AsV[2][512];
  __shared__ float A40s[64][44];
  __shared__ float Gc[WN_*WN_];
  __shared__ float crn[64];
  __shared__ float red[4][64];
  __shared__ float rns[64];
  int mode = get_mode(oneflag);
  int t = threadIdx.x;
  int rows0 = blockIdx.x*64;
  int c = rows0 / (BN_*RN_);
  int br0 = rows0 % (BN_*RN_);
  int w = t>>6, lane = t&63, q = lane>>4, cm = lane&15;

  // preamble: attention rows + Gram
  for (int i=t; i<64*WN_; i+=256){
    int rr = i&63, n = i>>6;
    A40s[rr][n] = attnr[((size_t)c*WN_+n)*(BN_*RN_) + br0 + rr];
  }
  for (int i=t; i<WN_*WN_; i+=256) Gc[i] = gram[(size_t)c*1600 + i];
  __syncthreads();
  if (t < 64){
    float mx=-1e30f;
#pragma unroll
    for (int n=0;n<WN_;n++) mx = fmaxf(mx, A40s[t][n]);
    float sum=0.f;
    float e[WN_];
#pragma unroll
    for (int n=0;n<WN_;n++){ e[n]=expf(SMOOTH_*(A40s[t][n]-mx)); sum+=e[n]; }
    float inv=1.f/sum;
#pragma unroll
    for (int n=0;n<WN_;n++) A40s[t][n]=e[n]*inv;
  }
  __syncthreads();
  {  // ||ctx_row||^2 = a^T G a, 4 threads per row
    int row = t>>2, pp = t&3;
    float gs = 0.f;
    for (int i=0;i<WN_;i++){
      float ai = A40s[row][i];
      float ps = 0.f;
      for (int j=pp; j<WN_; j+=4) ps += A40s[row][j]*Gc[i*WN_+j];
      gs += ai*ps;
    }
    gs += __shfl_xor(gs,1,64); gs += __shfl_xor(gs,2,64);
    if (pp==0) crn[row] = 1.f/(sqrtf(fmaxf(gs,0.f))+EPS_);
  }
  __syncthreads();

  f32x4 acc[4][4];
#pragma unroll
  for (int mt=0;mt<4;mt++)
#pragma unroll
    for (int nt=0;nt<4;nt++) acc[mt][nt] = (f32x4){0.f,0.f,0.f,0.f};

  for (int kt=0; kt<16; kt++){
    int p = kt&1;
#pragma unroll
    for (int h=0; h<2; h++){
      int fi = t + h*256;
      int mt = fi>>7, ks=(fi>>6)&1, ln=fi&63;
      int fq = ln>>4, fcm = ln&15;
      int row = mt*16+fcm;
      int kb = kt*64 + ks*32 + fq*8;
      float ctx8[8] = {0.f,0.f,0.f,0.f,0.f,0.f,0.f,0.f};
      for (int n=0;n<WN_;n++){
        float a = A40s[row][n];
        short8 cv = ld_frag8(cap, ((size_t)c*WN_+n)*DN_ + kb, mode);
#pragma unroll
        for (int j=0;j<8;j++) ctx8[j] += a*bf2f((u16)cv[j]);
      }
      short8 iv = ld_frag8(img, (size_t)(br0+row)*DN_ + kb, mode);
      float cr = crn[row];
      union { uint4 u; u16 s[8]; } xs;
#pragma unroll
      for (int j=0;j<8;j++){ float d = ctx8[j]*cr - bf2f((u16)iv[j]); xs.s[j] = f2bf(d*d); }
      AsV[p][fi & 511] = xs.u;
    }
    __syncthreads();
#pragma unroll
    for (int ks=0; ks<2; ks++){
      short8 a[4];
#pragma unroll
      for (int mt=0; mt<4; mt++){
        union { uint4 u; short8 s; } cv;
        cv.u = AsV[p][(mt*2+ks)*64 + lane];
        a[mt] = cv.s;
      }
#pragma unroll
      for (int nt=0; nt<4; nt++){
        int n = w*64 + nt*16 + cm;
        union { uint4 u; short8 s; } bv;
        bv.u = *(const uint4*)(WT + (((size_t)kt*SN_ + n)*64 + ks*32 + q*8));
#pragma unroll
        for (int mt=0; mt<4; mt++)
          acc[mt][nt] = __builtin_amdgcn_mfma_f32_16x16x32_bf16(a[mt], bv.s, acc[mt][nt], 0,0,0);
      }
    }
  }
  // bias + relu
  int sarr[4];
#pragma unroll
  for (int nt=0; nt<4; nt++){
    int s = w*64+nt*16+cm;
    sarr[nt] = s;
    float lb = ldf(loc_b, s, mode);
#pragma unroll
    for (int mt=0;mt<4;mt++)
#pragma unroll
      for (int r=0;r<4;r++) acc[mt][nt][r] = fmaxf(acc[mt][nt][r]+lb, 0.f);
  }
  // per-row sumsq -> rns
#pragma unroll
  for (int mt=0;mt<4;mt++)
#pragma unroll
  for (int r=0;r<4;r++){
    float v=0.f;
#pragma unroll
    for (int nt=0;nt<4;nt++) v += acc[mt][nt][r]*acc[mt][nt][r];
    v += __shfl_xor(v,1,64); v += __shfl_xor(v,2,64);
    v += __shfl_xor(v,4,64); v += __shfl_xor(v,8,64);
    if (cm==0) red[w][mt*16+q*4+r] = v;
  }
  __syncthreads();
  if (t<64) rns[t] = 1.f/(sqrtf(red[0][t]+red[1][t]+red[2][t]+red[3][t])+EPS_);
  __syncthreads();
  // scale + store
#pragma unroll
  for (int mt=0;mt<4;mt++)
#pragma unroll
  for (int r=0;r<4;r++){
    int rowl = mt*16+q*4+r;
    int br = br0+rowl; int b = br/RN_; int rr = br%RN_; int cb = c*BN_+b;
    float scl = rns[rowl]*wts_f[rows0+rowl];
    size_t obase = ((size_t)(cb*37) + 1 + rr)*SN_;
#pragma unroll
    for (int nt=0;nt<4;nt++) stf(out, obase + sarr[nt], acc[mt][nt][r]*scl, mode);
  }
}

extern "C" void kernel_launch(void* const* d_in, const int* in_sizes, int n_in,
                              void* d_out, int out_size, void* d_ws, size_t ws_size,
                              hipStream_t stream) {
  const void* img    = d_in[0];
  const void* cap    = d_in[1];
  const int*  adjs   = (const int*)d_in[3];
  const void* tsa_lw = d_in[5];
  const void* tsa_lb = d_in[6];
  const void* tsa_gw = d_in[7];
  const void* tsa_gb = d_in[8];
  const void* tsa_cw = d_in[9];
  const void* tsa_cb = d_in[10];
  const void* vl_w   = d_in[11];
  const void* vl_b   = d_in[12];
  const void* vbn_lg = d_in[13];
  const void* vbn_lb = d_in[14];
  const void* vg_w   = d_in[15];
  const void* vg_b   = d_in[16];
  const void* vbn_gg = d_in[17];
  const void* vbn_gb = d_in[18];
  const void* vc_w   = d_in[19];
  const void* vc_b   = d_in[20];
  const void* loc_w  = d_in[21];
  const void* loc_b  = d_in[22];
  const void* par_w  = d_in[23];
  const void* par_b  = d_in[24];
  const void* glo_w  = d_in[25];
  const void* glo_b  = d_in[26];
  const void* sim_w  = d_in[27];
  const void* sim_b  = d_in[28];
  const void* ln_g   = d_in[29];
  const void* ln_b   = d_in[30];
  const unsigned* oneflag = (const unsigned*)d_in[29];  // ln_g == ones: dtype probe
  void* out = d_out;

  // ---- workspace layout (float units), ~28.7 MB ----
  float* f = (float*)d_ws;
  float* U        = f;                      // 3,670,016: H | LE, later ATTNR
  float* H        = U;                      // 2304*1024 (dead after wraw_k)
  float* LE       = U + 2359296;            // 1280*1024 (dead after capglo_k)
  float* ATTNR    = U;                      // 1280*2304 (aliases H+LE)
  float* IMG_PARHf= U        + 3670016;     // 2304*1024 u16 = 1179648 floats
  float* IMG_AVE  = IMG_PARHf+ 1179648;     // 64*1024
  float* G        = IMG_AVE  + 65536;       // 64*1024
  float* WRAW     = G        + 65536;       // 2304
  float* RNORM    = WRAW     + 2304;        // 64
  float* IMG_GLO  = RNORM    + 64;          // 64*1024
  float* CAP_AVE  = IMG_GLO  + 65536;       // 32*1024
  float* GE       = CAP_AVE  + 32768;       // 32*1024
  float* CAP_GLO  = GE       + 32768;       // 32*1024
  float* SIMGLO   = CAP_GLO  + 32768;       // 32*64*256
  float* WTSR     = SIMGLO   + 524288;      // 32*64*36
  float* WTSF     = WTSR     + 73728;       // 32*64*36
  float* WTLOCf   = WTSF     + 73728;       // 1024*256 u16 = 131072 floats
  float* WTPARf   = WTLOCf   + 131072;      // 131072
  float* WTVLf    = WTPARf   + 131072;      // 1024*1024 u16 = 524288 floats
  float* WTTLf    = WTVLf    + 524288;      // 524288
  float* GRAM     = WTTLf    + 524288;      // 32*1600
  float* BNP      = GRAM     + 51200;       // 288*2
  u16* IMG_PARH = (u16*)IMG_PARHf;
  u16* WT_LOC = (u16*)WTLOCf;
  u16* WT_PAR = (u16*)WTPARf;
  u16* WT_VL  = (u16*)WTVLf;
  u16* WT_TL  = (u16*)WTTLf;

  // ---- prep: retiled weights + caption Grams ----
  prep_w_k<<<1024, 256, 0, stream>>>(loc_w, WT_LOC, 8, oneflag);
  prep_w_k<<<1024, 256, 0, stream>>>(par_w, WT_PAR, 8, oneflag);
  prep_w_k<<<4096, 256, 0, stream>>>(vl_w,  WT_VL, 10, oneflag);
  prep_w_k<<<4096, 256, 0, stream>>>(tsa_lw,WT_TL, 10, oneflag);
  gram_k<<<CN_, 256, 0, stream>>>(cap, GRAM, oneflag);

  // ---- caption-independent image pipeline ----
  mean_k<<<256, 256, 0, stream>>>(img, IMG_AVE, BN_, RN_, 1.f/RN_, oneflag);
  mean_k<<<128, 256, 0, stream>>>(cap, CAP_AVE, CN_, WN_, 1.f/WN_, oneflag);
  gemm_nt_mfma_k<<<dim3(16,36), 256, 0, stream>>>(img, (const void*)0, 0, WT_VL,
      vl_b, 1, 0, oneflag, H, BN_*RN_, DN_, DN_);
  bnl_sum_k<<<RN_*8, 256, 0, stream>>>(H, BNP);
  bnl_apply_k<<<BN_*RN_, 256, 0, stream>>>(H, vbn_lg, vbn_lb, BNP, oneflag);
  gemm_k<<<dim3(32,2), 256, 0, stream>>>(IMG_AVE, 1, vg_w, 0, vg_b, 1, 0, oneflag, G, BN_, DN_, DN_);
  bn_global_k<<<4, 256, 0, stream>>>(G, vbn_gg, vbn_gb, oneflag);
  wraw_k<<<BN_*RN_, 256, 0, stream>>>(H, G, vc_w, vc_b, WRAW, oneflag);
  glo_k<<<BN_, 256, 0, stream>>>(WRAW, img, IMG_GLO, RNORM, oneflag);
  partial_k<<<BN_*RN_, 256, 0, stream>>>(WRAW, adjs, img, RNORM, IMG_PARH, oneflag);

  // ---- caption pipeline ----
  gemm_nt_mfma_k<<<dim3(16,20), 256, 0, stream>>>(cap, (const void*)0, 0, WT_TL,
      tsa_lb, 1, 1, oneflag, LE, CN_*WN_, DN_, DN_);
  gemm_k<<<dim3(32,1), 256, 0, stream>>>(CAP_AVE, 1, tsa_gw, 0, tsa_gb, 1, 1, oneflag, GE, CN_, DN_, DN_);
  capglo_k<<<CN_, 256, 0, stream>>>(LE, GE, tsa_cw, tsa_cb, cap, CAP_GLO, oneflag);
  // ATTNR aliases H/LE — both dead by here (after wraw_k and capglo_k)
  gemm_nt_mfma_k<<<dim3(36,20), 256, 0, stream>>>(cap, img, 1, (const u16*)0,
      (const void*)0, 0, 0, oneflag, ATTNR, CN_*WN_, BN_*RN_, DN_);
  attn_norm_k<<<320, 256, 0, stream>>>(ATTNR);

  // ---- similarity heads ----
  simglo_k<<<CN_*BN_, 256, 0, stream>>>(IMG_GLO, CAP_GLO, glo_w, glo_b, SIMGLO, out, oneflag);
  wts_mfma_k<<<CN_*BN_*RN_/64, 256, 0, stream>>>(IMG_PARH, CAP_GLO, WT_PAR, par_b, SIMGLO, sim_w, sim_b, WTSR, oneflag);
  ln_k<<<8, 256, 0, stream>>>(WTSR, ln_g, ln_b, WTSF, oneflag);
  simloc_mfma_k<<<CN_*BN_*RN_/64, 256, 0, stream>>>(ATTNR, cap, img, WT_LOC, loc_b, WTSF, GRAM, out, oneflag);
}

// Round 6
// 1930.920 us; speedup vs baseline: 1.2703x; 1.2703x over previous
//
#include <hip/hip_runtime.h>

typedef unsigned short u16;
typedef __attribute__((ext_vector_type(8))) short short8;
typedef __attribute__((ext_vector_type(4))) float f32x4;

#define BN_ 64
#define CN_ 32
#define WN_ 40
#define RN_ 36
#define DN_ 1024
#define SN_ 256
#define KN_ 5
#define EPS_ 1e-8f
#define BNE_ 1e-5f
#define LNE_ 1e-5f
#define SMOOTH_ 9.0f

__device__ __forceinline__ float bf2f(u16 u){ return __uint_as_float(((unsigned)u)<<16); }
__device__ __forceinline__ u16 f2bf(float f){
  unsigned u = __float_as_uint(f);
  u += 0x7fffu + ((u>>16)&1u);
  return (u16)(u>>16);
}
// mode=1: tensor memory is float32. mode=0: bf16 (confirmed mode==0 on this harness)
__device__ __forceinline__ float ldf(const void* p, size_t i, int mode){
  return mode ? ((const float*)p)[i] : bf2f(((const u16*)p)[i]);
}
__device__ __forceinline__ void stf(void* p, size_t i, float v, int mode){
  if (mode) ((float*)p)[i] = v; else ((u16*)p)[i] = f2bf(v);
}
__device__ __forceinline__ int get_mode(const unsigned* oneflag){
  return (oneflag[0] == 0x3F800000u) ? 1 : 0;   // ln_g[0]==1.0f as f32
}
// load 8 consecutive elements as a bf16 fragment (16B vector load in mode 0)
__device__ __forceinline__ short8 ld_frag8(const void* p, size_t elem, int mode){
  if (mode == 0){
    union { uint4 u; short8 s; } cv;
    cv.u = *(const uint4*)((const u16*)p + elem);
    return cv.s;
  } else {
    const float* f = (const float*)p;
    short8 r;
#pragma unroll
    for (int j=0;j<8;j++) r[j] = (short)f2bf(f[elem+j]);
    return r;
  }
}

__device__ __forceinline__ float wave_sum(float v){
#pragma unroll
  for (int off=32; off>0; off>>=1) v += __shfl_down(v, off, 64);
  return v;
}
// blockDim.x == 256
__device__ float block_sum(float v, float* sc4){
  v = wave_sum(v);
  if ((threadIdx.x & 63)==0) sc4[threadIdx.x>>6] = v;
  __syncthreads();
  float r = sc4[0]+sc4[1]+sc4[2]+sc4[3];
  __syncthreads();
  return r;
}

// ---------------- mean over middle axis
__global__ void mean_k(const void* X, float* out, int G, int L, float inv, const unsigned* oneflag){
  int mode = get_mode(oneflag);
  int idx = blockIdx.x*256 + threadIdx.x;
  if (idx >= G*DN_) return;
  int g = idx >> 10, d = idx & 1023;
  size_t base = (size_t)g*L*DN_ + d;
  float s = 0.f;
  for (int l=0; l<L; l++) s += ldf(X, base + (size_t)l*DN_, mode);
  out[idx] = s*inv;
}

// ---------------- retile weight W (K=1024 rows, N cols, k-major) -> WT[kt][n][64] bf16
__global__ void prep_w_k(const void* W, u16* WT, int nlog2, const unsigned* oneflag){
  int mode = get_mode(oneflag);
  int N = 1 << nlog2;
  int idx = blockIdx.x*256 + threadIdx.x;
  if (idx >= (DN_<<nlog2)) return;
  int k = idx >> nlog2, n = idx & (N-1);
  float v = ldf(W, idx, mode);
  WT[(((size_t)(k>>6))*N + n)*64 + (k&63)] = f2bf(v);
}

// ================= generic MFMA NT-GEMM (zero LDS / zero barriers) =================
__global__ __launch_bounds__(256) void gemm_nt_mfma_k(
    const void* A, const void* B, int bt, const u16* WT,
    const void* bias, int has_bias, int act, const unsigned* oneflag,
    float* C, int M, int N, int K){
  int mode = get_mode(oneflag);
  int t = threadIdx.x;
  int w = t>>6, lane = t&63, q = lane>>4, cm = lane&15;
  int m0 = blockIdx.y*64, n0 = blockIdx.x*64 + w*16;
  f32x4 acc[4];
#pragma unroll
  for (int mt=0;mt<4;mt++) acc[mt] = (f32x4){0.f,0.f,0.f,0.f};
  int nkt = K>>6;
  for (int kt=0; kt<nkt; kt++){
#pragma unroll
    for (int ks=0; ks<2; ks++){
      int kb = kt*64 + ks*32 + q*8;
      short8 b;
      if (bt) b = ld_frag8(B, (size_t)(n0+cm)*K + kb, mode);
      else {
        union { uint4 u; short8 s; } cv;
        cv.u = *(const uint4*)(WT + (((size_t)kt*N + n0+cm)*64 + ks*32 + q*8));
        b = cv.s;
      }
#pragma unroll
      for (int mt=0; mt<4; mt++){
        short8 a = ld_frag8(A, (size_t)(m0+mt*16+cm)*K + kb, mode);
        acc[mt] = __builtin_amdgcn_mfma_f32_16x16x32_bf16(a, b, acc[mt], 0,0,0);
      }
    }
  }
  float bv = has_bias ? ldf(bias, n0+cm, mode) : 0.f;
#pragma unroll
  for (int mt=0; mt<4; mt++){
#pragma unroll
    for (int r=0; r<4; r++){
      int m = m0 + mt*16 + q*4 + r;
      float v = acc[mt][r] + bv;
      if (act==1) v = tanhf(v);
      C[(size_t)m*N + n0+cm] = v;
    }
  }
}

// ---------------- BN-local split
__global__ void bnl_sum_k(const float* h, float* bnp){
  __shared__ float sc[4];
  int r = blockIdx.x>>3, bg = blockIdx.x&7;
  float s=0.f, s2=0.f;
  for (int bb=0; bb<8; bb++){
    int b = bg*8+bb;
    const float* p = h + ((size_t)b*RN_ + r)*DN_;
    for (int d=threadIdx.x; d<DN_; d+=256){ float x=p[d]; s+=x; s2+=x*x; }
  }
  s  = block_sum(s,  sc);
  s2 = block_sum(s2, sc);
  if (threadIdx.x==0){ bnp[blockIdx.x*2]=s; bnp[blockIdx.x*2+1]=s2; }
}
__global__ void bnl_apply_k(float* h, const void* gg_, const void* bb_,
                            const float* bnp, const unsigned* oneflag){
  int mode = get_mode(oneflag);
  int row = blockIdx.x; int r = row % RN_;
  float s=0.f, s2=0.f;
  for (int j=0;j<8;j++){ s += bnp[(r*8+j)*2]; s2 += bnp[(r*8+j)*2+1]; }
  float inv = 1.f/(float)(BN_*DN_);
  float mu = s*inv;
  float var = s2*inv - mu*mu;
  float rstd = rsqrtf(var + BNE_);
  float gg = ldf(gg_, r, mode), bb = ldf(bb_, r, mode);
  float* p = h + (size_t)row*DN_;
  for (int d=threadIdx.x; d<DN_; d+=256) p[d] = tanhf((p[d]-mu)*rstd*gg + bb);
}

// ---------------- BN over batch per feature + tanh
__global__ void bn_global_k(float* g, const void* gg_, const void* bb_, const unsigned* oneflag){
  int mode = get_mode(oneflag);
  int d = blockIdx.x*256 + threadIdx.x;
  if (d >= DN_) return;
  float s=0.f, s2=0.f;
  for (int b=0;b<BN_;b++){ float x=g[(size_t)b*DN_+d]; s+=x; s2+=x*x; }
  float m = s/(float)BN_;
  float var = s2/(float)BN_ - m*m;
  float rstd = rsqrtf(var + BNE_);
  float ga=ldf(gg_,d,mode), be=ldf(bb_,d,mode);
  for (int b=0;b<BN_;b++){
    size_t i=(size_t)b*DN_+d;
    g[i] = tanhf((g[i]-m)*rstd*ga + be);
  }
}

// ---------------- VALU tiled GEMM (two tiny f32-A GEMMs)
__global__ void gemm_k(const void* A, int a_ws, const void* B, int transb,
                       const void* bias, int has_bias, int act,
                       const unsigned* oneflag, float* C, int M, int N, int K){
  __shared__ float As[32][33];
  __shared__ float Bs[32][33];
  int mode = get_mode(oneflag);
  int n0 = blockIdx.x*32, m0 = blockIdx.y*32;
  int tid = threadIdx.x;
  int tx = tid & 15, ty = tid >> 4;
  float a00=0,a01=0,a10=0,a11=0;
  for (int kt=0; kt<K; kt+=32){
    for (int l=0; l<4; l++){
      int idx = tid + l*256;
      {
        int i = idx >> 5, k = idx & 31;
        int m = m0 + i;
        float v = 0.f;
        if (m < M){
          size_t off = (size_t)m*K + kt + k;
          v = a_ws ? ((const float*)A)[off] : ldf(A, off, mode);
        }
        As[i][k] = v;
      }
      if (!transb){
        int k = idx >> 5, j = idx & 31;
        int n = n0 + j;
        Bs[k][j] = (n<N) ? ldf(B, (size_t)(kt+k)*N + n, mode) : 0.f;
      } else {
        int j = idx >> 5, k = idx & 31;
        int n = n0 + j;
        Bs[k][j] = (n<N) ? ldf(B, (size_t)n*K + kt + k, mode) : 0.f;
      }
    }
    __syncthreads();
#pragma unroll
    for (int kk=0; kk<32; kk++){
      float x0 = As[ty][kk], x1 = As[ty+16][kk];
      float y0 = Bs[kk][tx], y1 = Bs[kk][tx+16];
      a00 += x0*y0; a01 += x0*y1; a10 += x1*y0; a11 += x1*y1;
    }
    __syncthreads();
  }
  float acc[2][2] = {{a00,a01},{a10,a11}};
  for (int i=0;i<2;i++){
    for (int j=0;j<2;j++){
      int m = m0 + ty + i*16, n = n0 + tx + j*16;
      if (m<M && n<N){
        float v = acc[i][j];
        if (has_bias) v += ldf(bias, n, mode);
        if (act==1) v = tanhf(v);
        C[(size_t)m*N + n] = v;
      }
    }
  }
}

// ---------------- weights_raw[b,r]
__global__ void wraw_k(const float* lemb, const float* gemb, const void* vc_w, const void* vc_b,
                       float* wraw, const unsigned* oneflag){
  __shared__ float sc[4];
  int mode = get_mode(oneflag);
  int br = blockIdx.x; int b = br / RN_;
  const float* lp = lemb + (size_t)br*DN_;
  const float* gp = gemb + (size_t)b*DN_;
  float s=0.f;
  for (int d=threadIdx.x; d<DN_; d+=256) s += lp[d]*gp[d]*ldf(vc_w,d,mode);
  s = block_sum(s, sc);
  if (threadIdx.x==0) wraw[br] = s + ldf(vc_b,0,mode);
}

// ---------------- region softmax -> weighted sum -> l2norm
__global__ void glo_k(const float* wraw, const void* img, float* img_glo, float* rnorm,
                      const unsigned* oneflag){
  __shared__ float sc[4];
  __shared__ float wsm[RN_];
  __shared__ float srn;
  int mode = get_mode(oneflag);
  int b = blockIdx.x;
  if (threadIdx.x==0){
    float mx=-1e30f;
    for (int r=0;r<RN_;r++) mx = fmaxf(mx, wraw[b*RN_+r]);
    float sum=0.f;
    for (int r=0;r<RN_;r++){ float e=expf(wraw[b*RN_+r]-mx); wsm[r]=e; sum+=e; }
    float inv=1.f/sum;
    for (int r=0;r<RN_;r++) wsm[r]*=inv;
  }
  __syncthreads();
  float ng[4]; float s2=0.f;
#pragma unroll
  for (int j=0;j<4;j++){
    int d = threadIdx.x + j*256;
    float s=0.f;
    for (int r=0;r<RN_;r++) s += wsm[r]*ldf(img, ((size_t)b*RN_+r)*DN_ + d, mode);
    ng[j]=s; s2 += s*s;
  }
  s2 = block_sum(s2, sc);
  if (threadIdx.x==0) srn = 1.f/(sqrtf(s2)+EPS_);
  __syncthreads();
  float rn = srn;
#pragma unroll
  for (int j=0;j<4;j++) img_glo[(size_t)b*DN_ + threadIdx.x + j*256] = ng[j]*rn;
  if (threadIdx.x==0) rnorm[b]=rn;
}

// ---------------- partial embeddings (output bf16)
__global__ void partial_k(const float* wraw, const int* adjs, const void* img,
                          const float* rnorm, u16* img_parh, const unsigned* oneflag){
  __shared__ float wg[KN_];
  __shared__ int eff[KN_];
  int mode = get_mode(oneflag);
  int br = blockIdx.x; int b = br / RN_; int r = br % RN_;
  if (threadIdx.x==0){
    int cnt=0;
    const int* ap = adjs + (size_t)br*RN_;
    for (int j=0;j<RN_ && cnt<KN_;j++) if (ap[j]==1) eff[cnt++]=j;
    for (int k=cnt;k<KN_;k++) eff[k]=r;
    float v[KN_]; float mx=-1e30f;
    for (int k=0;k<KN_;k++){ v[k]=wraw[b*RN_+eff[k]]; mx=fmaxf(mx,v[k]); }
    float sum=0.f;
    for (int k=0;k<KN_;k++){ v[k]=expf(v[k]-mx); sum+=v[k]; }
    float inv=1.f/sum;
    for (int k=0;k<KN_;k++) wg[k]=v[k]*inv;
  }
  __syncthreads();
  float rn = rnorm[b];
  for (int d=threadIdx.x; d<DN_; d+=256){
    float s=0.f;
#pragma unroll
    for (int k=0;k<KN_;k++) s += wg[k]*ldf(img, ((size_t)b*RN_+eff[k])*DN_ + d, mode);
    img_parh[(size_t)br*DN_ + d] = f2bf(s*rn);
  }
}

// ---------------- caption attention pool -> cap_glo
__global__ void capglo_k(const float* le, const float* ge, const void* tsa_cw, const void* tsa_cb,
                         const void* cap, float* cap_glo, const unsigned* oneflag){
  __shared__ float sc[4];
  __shared__ float score[WN_];
  __shared__ float srn;
  int mode = get_mode(oneflag);
  int c = blockIdx.x;
  int t = threadIdx.x;
  float gw[4];
#pragma unroll
  for (int j=0;j<4;j++){ int d=t+j*256; gw[j] = ge[(size_t)c*DN_+d]*ldf(tsa_cw,d,mode); }
  float cb0 = ldf(tsa_cb,0,mode);
  for (int n=0;n<WN_;n++){
    const float* lp = le + ((size_t)c*WN_+n)*DN_;
    float s=0.f;
#pragma unroll
    for (int j=0;j<4;j++) s += lp[t+j*256]*gw[j];
    s = block_sum(s, sc);
    if (t==0) score[n] = s + cb0;
  }
  __syncthreads();
  if (t==0){
    float mx=-1e30f;
    for (int n=0;n<WN_;n++) mx=fmaxf(mx,score[n]);
    float sum=0.f;
    for (int n=0;n<WN_;n++){ float e=expf(score[n]-mx); score[n]=e; sum+=e; }
    float inv=1.f/sum;
    for (int n=0;n<WN_;n++) score[n]*=inv;
  }
  __syncthreads();
  float v[4]; float s2=0.f;
#pragma unroll
  for (int j=0;j<4;j++){
    int d=t+j*256;
    float s=0.f;
    for (int n=0;n<WN_;n++) s += score[n]*ldf(cap, ((size_t)c*WN_+n)*DN_ + d, mode);
    v[j]=s; s2+=s*s;
  }
  s2 = block_sum(s2, sc);
  if (t==0) srn = 1.f/(sqrtf(s2)+EPS_);
  __syncthreads();
#pragma unroll
  for (int j=0;j<4;j++) cap_glo[(size_t)c*DN_ + t + j*256] = v[j]*srn;
}

// ---------------- leaky_relu + l2norm over region segments; block per (c,n) row
__global__ void attn_norm_k(float* attn){
  __shared__ float buf[BN_*RN_];
  int row = blockIdx.x;           // c*WN_+n
  int t = threadIdx.x;
  float* p = attn + (size_t)row*(BN_*RN_);
  for (int i=t; i<BN_*RN_; i+=256){
    float x = p[i];
    buf[i] = (x>=0.f)? x : 0.1f*x;
  }
  __syncthreads();
  if (t < BN_){
    float s2=0.f;
#pragma unroll
    for (int r=0;r<RN_;r++){ float x=buf[t*RN_+r]; s2+=x*x; }
    float rn = 1.f/(sqrtf(s2)+EPS_);
#pragma unroll
    for (int r=0;r<RN_;r++) buf[t*RN_+r] *= rn;
  }
  __syncthreads();
  for (int i=t; i<BN_*RN_; i+=256) p[i] = buf[i];
}

// ---------------- per-caption Gram
__global__ void gram_k(const void* cap, float* gram, const unsigned* oneflag){
  __shared__ float capS[WN_][128];
  int mode = get_mode(oneflag);
  int c = blockIdx.x, t = threadIdx.x;
  float acc[7];
  int pi[7], pj[7];
#pragma unroll
  for (int u=0; u<7; u++){
    acc[u]=0.f;
    int p = t + u*256;
    pi[u] = p/40; pj[u] = p%40;
    if (pi[u] >= WN_) pi[u] = 0;
  }
  for (int k0=0; k0<DN_; k0+=128){
    for (int i=t; i<WN_*128; i+=256){
      int n = i>>7, kk = i&127;
      capS[n][kk] = ldf(cap, ((size_t)c*WN_+n)*DN_ + k0+kk, mode);
    }
    __syncthreads();
#pragma unroll
    for (int u=0; u<7; u++){
      if (t + u*256 < 1600){
        float s=0.f;
        for (int kk=0; kk<128; kk++) s += capS[pi[u]][kk]*capS[pj[u]][kk];
        acc[u] += s;
      }
    }
    __syncthreads();
  }
#pragma unroll
  for (int u=0; u<7; u++)
    if (t + u*256 < 1600) gram[(size_t)c*1600 + t + u*256] = acc[u];
}

// ---------------- sim_glo
__global__ void simglo_k(const float* img_glo, const float* cap_glo, const void* glo_w,
                         const void* glo_b, float* simglo_ws, void* out, const unsigned* oneflag){
  __shared__ float X[DN_];
  __shared__ float sc[4];
  __shared__ float srn;
  int mode = get_mode(oneflag);
  int cb = blockIdx.x; int c = cb >> 6; int b = cb & 63;
  int t = threadIdx.x;
#pragma unroll
  for (int j=0;j<4;j++){
    int d=t+j*256;
    float dif = img_glo[(size_t)b*DN_+d] - cap_glo[(size_t)c*DN_+d];
    X[d] = dif*dif;
  }
  __syncthreads();
  float acc=0.f;
  for (int k=0;k<DN_;k++) acc += X[k]*ldf(glo_w, (size_t)k*SN_ + t, mode);
  acc += ldf(glo_b, t, mode);
  acc = fmaxf(acc, 0.f);
  float s2 = block_sum(acc*acc, sc);
  if (t==0) srn = 1.f/(sqrtf(s2)+EPS_);
  __syncthreads();
  float o = acc*srn;
  simglo_ws[(size_t)cb*SN_ + t] = o;
  stf(out, (size_t)cb*37*SN_ + t, o, mode);
  stf(out, (size_t)CN_*BN_*37*SN_ + (size_t)cb*SN_ + t, o, mode);
}

// ---- fused sim_par -> wts_raw (round-5 version; verified)
__global__ __launch_bounds__(256) void wts_mfma_k(const u16* img_parh, const float* cap_glo,
    const u16* WT, const void* par_b, const float* simglo, const void* sim_w,
    const void* sim_b, float* wts_raw, const unsigned* oneflag){
  __shared__ uint4 AsV[2][512];
  __shared__ float red[4][64];
  __shared__ float rns[64];
  int mode = get_mode(oneflag);
  int t = threadIdx.x;
  int rows0 = blockIdx.x*64;
  int c = rows0 / (BN_*RN_);
  int br0 = rows0 % (BN_*RN_);
  int w = t>>6, lane = t&63, q = lane>>4, cm = lane&15;
  f32x4 acc[4][4];
#pragma unroll
  for (int mt=0;mt<4;mt++)
#pragma unroll
    for (int nt=0;nt<4;nt++) acc[mt][nt] = (f32x4){0.f,0.f,0.f,0.f};

  for (int kt=0; kt<16; kt++){
    int p = kt&1;
#pragma unroll
    for (int h=0; h<2; h++){
      int fi = t + h*256;
      int mt = fi>>7, ks=(fi>>6)&1, ln=fi&63;
      int fq = ln>>4, fcm = ln&15;
      int row = mt*16+fcm;
      int kb = kt*64 + ks*32 + fq*8;
      union { uint4 u; u16 s[8]; } pv;
      pv.u = *(const uint4*)(img_parh + (size_t)(br0+row)*DN_ + kb);
      const float* cg = cap_glo + (size_t)c*DN_ + kb;
      union { uint4 u; u16 s[8]; } xs;
#pragma unroll
      for (int j=0;j<8;j++){ float d = bf2f(pv.s[j]) - cg[j]; xs.s[j] = f2bf(d*d); }
      AsV[p][fi & 511] = xs.u;
    }
    __syncthreads();
#pragma unroll
    for (int ks=0; ks<2; ks++){
      short8 a[4];
#pragma unroll
      for (int mt=0; mt<4; mt++){
        union { uint4 u; short8 s; } cv;
        cv.u = AsV[p][(mt*2+ks)*64 + lane];
        a[mt] = cv.s;
      }
#pragma unroll
      for (int nt=0; nt<4; nt++){
        int n = w*64 + nt*16 + cm;
        union { uint4 u; short8 s; } bv;
        bv.u = *(const uint4*)(WT + (((size_t)kt*SN_ + n)*64 + ks*32 + q*8));
#pragma unroll
        for (int mt=0; mt<4; mt++)
          acc[mt][nt] = __builtin_amdgcn_mfma_f32_16x16x32_bf16(a[mt], bv.s, acc[mt][nt], 0,0,0);
      }
    }
  }
  int sarr[4]; float sw[4];
#pragma unroll
  for (int nt=0; nt<4; nt++){
    int s = w*64+nt*16+cm;
    sarr[nt] = s;
    float pb = ldf(par_b, s, mode);
    sw[nt] = ldf(sim_w, s, mode);
#pragma unroll
    for (int mt=0;mt<4;mt++)
#pragma unroll
      for (int r=0;r<4;r++) acc[mt][nt][r] = fmaxf(acc[mt][nt][r]+pb, 0.f);
  }
#pragma unroll
  for (int mt=0;mt<4;mt++)
#pragma unroll
  for (int r=0;r<4;r++){
    float v=0.f;
#pragma unroll
    for (int nt=0;nt<4;nt++) v += acc[mt][nt][r]*acc[mt][nt][r];
    v += __shfl_xor(v,1,64); v += __shfl_xor(v,2,64);
    v += __shfl_xor(v,4,64); v += __shfl_xor(v,8,64);
    if (cm==0) red[w][mt*16+q*4+r] = v;
  }
  __syncthreads();
  if (t<64) rns[t] = 1.f/(sqrtf(red[0][t]+red[1][t]+red[2][t]+red[3][t])+EPS_);
  __syncthreads();
#pragma unroll
  for (int mt=0;mt<4;mt++)
#pragma unroll
  for (int r=0;r<4;r++){
    int rowl = mt*16+q*4+r;
    int br = br0+rowl; int b = br/RN_; int cb = c*BN_+b;
    float v=0.f;
#pragma unroll
    for (int nt=0;nt<4;nt++) v += acc[mt][nt][r]*simglo[(size_t)cb*SN_+sarr[nt]]*sw[nt];
    v += __shfl_xor(v,1,64); v += __shfl_xor(v,2,64);
    v += __shfl_xor(v,4,64); v += __shfl_xor(v,8,64);
    if (cm==0) red[w][rowl] = v;
  }
  __syncthreads();
  if (t<64) wts_raw[rows0+t] = (red[0][t]+red[1][t]+red[2][t]+red[3][t])*rns[t] + ldf(sim_b,0,mode);
}

// ---------------- LN over regions + sigmoid
__global__ void ln_k(const float* wts_raw, const void* ln_g, const void* ln_b,
                     float* wts_f, const unsigned* oneflag){
  int mode = get_mode(oneflag);
  int cb = blockIdx.x*256 + threadIdx.x;
  if (cb >= CN_*BN_) return;
  const float* p = wts_raw + (size_t)cb*RN_;
  float s=0.f, s2=0.f;
#pragma unroll
  for (int r=0;r<RN_;r++){ float x=p[r]; s+=x; s2+=x*x; }
  float m = s/(float)RN_;
  float v = s2/(float)RN_ - m*m;
  float rstd = rsqrtf(v + LNE_);
  float* q = wts_f + (size_t)cb*RN_;
#pragma unroll
  for (int r=0;r<RN_;r++){
    float x = (p[r]-m)*rstd*ldf(ln_g,r,mode) + ldf(ln_b,r,mode);
    q[r] = 1.f/(1.f+expf(-x));
  }
}

// ---- fused simloc: softmax -> ctx via MFMA -> X -> sim_loc MFMA -> *wts -> out
// Block: 64 rows of one caption. ctx slab [64 rows][64 k] = Ps[64][40pad] @ capT[40pad][64].
__global__ __launch_bounds__(256) void simloc_mfma_k(const float* attnr, const void* cap,
    const void* img, const u16* WT, const void* loc_b, const float* wts_f,
    const float* gram, void* out, const unsigned* oneflag){
  __shared__ float A40s[64][41];
  __shared__ u16 Ps[64][72];      // softmax P, bf16, words 40..63 zero
  __shared__ u16 capT[64][72];    // [kelem][word], words 40..63 zero
  __shared__ u16 Xs[64][72];      // X slab, bf16
  __shared__ float Gc[WN_*WN_];
  __shared__ float crn[64];
  __shared__ float red[4][64];
  __shared__ float rns[64];
  int mode = get_mode(oneflag);
  int t = threadIdx.x;
  int rows0 = blockIdx.x*64;
  int c = rows0 / (BN_*RN_);
  int br0 = rows0 % (BN_*RN_);
  int w = t>>6, lane = t&63, q = lane>>4, cm = lane&15;

  // ---- preamble: attention rows, Gram, zero pads
  for (int i=t; i<64*WN_; i+=256){
    int rr = i&63, n = i>>6;
    A40s[rr][n] = attnr[((size_t)c*WN_+n)*(BN_*RN_) + br0 + rr];
  }
  for (int i=t; i<WN_*WN_; i+=256) Gc[i] = gram[(size_t)c*1600 + i];
  for (int i=t; i<64*24; i+=256){   // zero capT word pad 40..63
    int ke = i/24, wd = 40 + (i - ke*24);
    capT[ke][wd] = 0;
  }
  __syncthreads();
  // softmax over words (x SMOOTH); also emit bf16 P with zero pad
  if (t < 64){
    float mx=-1e30f;
#pragma unroll
    for (int n=0;n<WN_;n++) mx = fmaxf(mx, A40s[t][n]);
    float sum=0.f;
    float e[WN_];
#pragma unroll
    for (int n=0;n<WN_;n++){ e[n]=expf(SMOOTH_*(A40s[t][n]-mx)); sum+=e[n]; }
    float inv=1.f/sum;
#pragma unroll
    for (int n=0;n<WN_;n++){ float pv=e[n]*inv; A40s[t][n]=pv; Ps[t][n]=f2bf(pv); }
#pragma unroll
    for (int n=WN_;n<64;n++) Ps[t][n]=0;
  }
  __syncthreads();
  {  // ||ctx_row||^2 = p^T G p (f32 P), 4 threads per row
    int row = t>>2, pp = t&3;
    float gs = 0.f;
    for (int i=0;i<WN_;i++){
      float ai = A40s[row][i];
      float ps = 0.f;
      for (int j=pp; j<WN_; j+=4) ps += A40s[row][j]*Gc[i*WN_+j];
      gs += ai*ps;
    }
    gs += __shfl_xor(gs,1,64); gs += __shfl_xor(gs,2,64);
    if (pp==0) crn[row] = 1.f/(sqrtf(fmaxf(gs,0.f))+EPS_);
  }

  f32x4 acc[4][4];
#pragma unroll
  for (int mt=0;mt<4;mt++)
#pragma unroll
    for (int nt=0;nt<4;nt++) acc[mt][nt] = (f32x4){0.f,0.f,0.f,0.f};
  __syncthreads();

  for (int kt=0; kt<16; kt++){
    // (a) stage capT[kelem][word] transposed from cap slab
    for (int i=t; i<WN_*8; i+=256){
      int wd = i>>3, kg = i&7;
      short8 cv = ld_frag8(cap, ((size_t)c*WN_+wd)*DN_ + kt*64 + kg*8, mode);
#pragma unroll
      for (int j=0;j<8;j++) capT[kg*8+j][wd] = (u16)cv[j];
    }
    __syncthreads();
    // (c) ctx MFMA: wave w owns kelem tile [w*16, w*16+16)
    f32x4 ctxacc[4];
#pragma unroll
    for (int mt=0;mt<4;mt++) ctxacc[mt] = (f32x4){0.f,0.f,0.f,0.f};
#pragma unroll
    for (int ks=0; ks<2; ks++){
      union { uint4 u; short8 s; } bv;
      bv.u = *(const uint4*)(&capT[w*16+cm][ks*32+q*8]);
#pragma unroll
      for (int mt=0; mt<4; mt++){
        union { uint4 u; short8 s; } av;
        av.u = *(const uint4*)(&Ps[mt*16+cm][ks*32+q*8]);
        ctxacc[mt] = __builtin_amdgcn_mfma_f32_16x16x32_bf16(av.s, bv.s, ctxacc[mt], 0,0,0);
      }
    }
    // (d) X formation: wave-private columns w*16+cm
#pragma unroll
    for (int mt=0; mt<4; mt++){
#pragma unroll
      for (int r=0; r<4; r++){
        int row = mt*16 + q*4 + r;
        float iv = ldf(img, (size_t)(br0+row)*DN_ + kt*64 + w*16 + cm, mode);
        float x = ctxacc[mt][r]*crn[row] - iv;
        Xs[row][w*16+cm] = f2bf(x*x);
      }
    }
    __syncthreads();
    // (f) main MFMA from Xs + WT
#pragma unroll
    for (int ks=0; ks<2; ks++){
      short8 a[4];
#pragma unroll
      for (int mt=0; mt<4; mt++){
        union { uint4 u; short8 s; } av;
        av.u = *(const uint4*)(&Xs[mt*16+cm][ks*32+q*8]);
        a[mt] = av.s;
      }
#pragma unroll
      for (int nt=0; nt<4; nt++){
        int n = w*64 + nt*16 + cm;
        union { uint4 u; short8 s; } bv;
        bv.u = *(const uint4*)(WT + (((size_t)kt*SN_ + n)*64 + ks*32 + q*8));
#pragma unroll
        for (int mt=0; mt<4; mt++)
          acc[mt][nt] = __builtin_amdgcn_mfma_f32_16x16x32_bf16(a[mt], bv.s, acc[mt][nt], 0,0,0);
      }
    }
    __syncthreads();
  }
  // epilogue: bias + relu
  int sarr[4];
#pragma unroll
  for (int nt=0; nt<4; nt++){
    int s = w*64+nt*16+cm;
    sarr[nt] = s;
    float lb = ldf(loc_b, s, mode);
#pragma unroll
    for (int mt=0;mt<4;mt++)
#pragma unroll
      for (int r=0;r<4;r++) acc[mt][nt][r] = fmaxf(acc[mt][nt][r]+lb, 0.f);
  }
#pragma unroll
  for (int mt=0;mt<4;mt++)
#pragma unroll
  for (int r=0;r<4;r++){
    float v=0.f;
#pragma unroll
    for (int nt=0;nt<4;nt++) v += acc[mt][nt][r]*acc[mt][nt][r];
    v += __shfl_xor(v,1,64); v += __shfl_xor(v,2,64);
    v += __shfl_xor(v,4,64); v += __shfl_xor(v,8,64);
    if (cm==0) red[w][mt*16+q*4+r] = v;
  }
  __syncthreads();
  if (t<64) rns[t] = 1.f/(sqrtf(red[0][t]+red[1][t]+red[2][t]+red[3][t])+EPS_);
  __syncthreads();
#pragma unroll
  for (int mt=0;mt<4;mt++)
#pragma unroll
  for (int r=0;r<4;r++){
    int rowl = mt*16+q*4+r;
    int br = br0+rowl; int b = br/RN_; int rr = br%RN_; int cb = c*BN_+b;
    float scl = rns[rowl]*wts_f[rows0+rowl];
    size_t obase = ((size_t)(cb*37) + 1 + rr)*SN_;
#pragma unroll
    for (int nt=0;nt<4;nt++) stf(out, obase + sarr[nt], acc[mt][nt][r]*scl, mode);
  }
}

extern "C" void kernel_launch(void* const* d_in, const int* in_sizes, int n_in,
                              void* d_out, int out_size, void* d_ws, size_t ws_size,
                              hipStream_t stream) {
  const void* img    = d_in[0];
  const void* cap    = d_in[1];
  const int*  adjs   = (const int*)d_in[3];
  const void* tsa_lw = d_in[5];
  const void* tsa_lb = d_in[6];
  const void* tsa_gw = d_in[7];
  const void* tsa_gb = d_in[8];
  const void* tsa_cw = d_in[9];
  const void* tsa_cb = d_in[10];
  const void* vl_w   = d_in[11];
  const void* vl_b   = d_in[12];
  const void* vbn_lg = d_in[13];
  const void* vbn_lb = d_in[14];
  const void* vg_w   = d_in[15];
  const void* vg_b   = d_in[16];
  const void* vbn_gg = d_in[17];
  const void* vbn_gb = d_in[18];
  const void* vc_w   = d_in[19];
  const void* vc_b   = d_in[20];
  const void* loc_w  = d_in[21];
  const void* loc_b  = d_in[22];
  const void* par_w  = d_in[23];
  const void* par_b  = d_in[24];
  const void* glo_w  = d_in[25];
  const void* glo_b  = d_in[26];
  const void* sim_w  = d_in[27];
  const void* sim_b  = d_in[28];
  const void* ln_g   = d_in[29];
  const void* ln_b   = d_in[30];
  const unsigned* oneflag = (const unsigned*)d_in[29];  // ln_g == ones: dtype probe
  void* out = d_out;

  // ---- workspace layout (float units), ~28.7 MB ----
  float* f = (float*)d_ws;
  float* U        = f;                      // 3,670,016: H | LE, later ATTNR
  float* H        = U;                      // 2304*1024 (dead after wraw_k)
  float* LE       = U + 2359296;            // 1280*1024 (dead after capglo_k)
  float* ATTNR    = U;                      // 1280*2304 (aliases H+LE)
  float* IMG_PARHf= U        + 3670016;     // 2304*1024 u16 = 1179648 floats
  float* IMG_AVE  = IMG_PARHf+ 1179648;     // 64*1024
  float* G        = IMG_AVE  + 65536;       // 64*1024
  float* WRAW     = G        + 65536;       // 2304
  float* RNORM    = WRAW     + 2304;        // 64
  float* IMG_GLO  = RNORM    + 64;          // 64*1024
  float* CAP_AVE  = IMG_GLO  + 65536;       // 32*1024
  float* GE       = CAP_AVE  + 32768;       // 32*1024
  float* CAP_GLO  = GE       + 32768;       // 32*1024
  float* SIMGLO   = CAP_GLO  + 32768;       // 32*64*256
  float* WTSR     = SIMGLO   + 524288;      // 32*64*36
  float* WTSF     = WTSR     + 73728;       // 32*64*36
  float* WTLOCf   = WTSF     + 73728;       // 1024*256 u16 = 131072 floats
  float* WTPARf   = WTLOCf   + 131072;      // 131072
  float* WTVLf    = WTPARf   + 131072;      // 1024*1024 u16 = 524288 floats
  float* WTTLf    = WTVLf    + 524288;      // 524288
  float* GRAM     = WTTLf    + 524288;      // 32*1600
  float* BNP      = GRAM     + 51200;       // 288*2
  u16* IMG_PARH = (u16*)IMG_PARHf;
  u16* WT_LOC = (u16*)WTLOCf;
  u16* WT_PAR = (u16*)WTPARf;
  u16* WT_VL  = (u16*)WTVLf;
  u16* WT_TL  = (u16*)WTTLf;

  // ---- prep: retiled weights + caption Grams ----
  prep_w_k<<<1024, 256, 0, stream>>>(loc_w, WT_LOC, 8, oneflag);
  prep_w_k<<<1024, 256, 0, stream>>>(par_w, WT_PAR, 8, oneflag);
  prep_w_k<<<4096, 256, 0, stream>>>(vl_w,  WT_VL, 10, oneflag);
  prep_w_k<<<4096, 256, 0, stream>>>(tsa_lw,WT_TL, 10, oneflag);
  gram_k<<<CN_, 256, 0, stream>>>(cap, GRAM, oneflag);

  // ---- caption-independent image pipeline ----
  mean_k<<<256, 256, 0, stream>>>(img, IMG_AVE, BN_, RN_, 1.f/RN_, oneflag);
  mean_k<<<128, 256, 0, stream>>>(cap, CAP_AVE, CN_, WN_, 1.f/WN_, oneflag);
  gemm_nt_mfma_k<<<dim3(16,36), 256, 0, stream>>>(img, (const void*)0, 0, WT_VL,
      vl_b, 1, 0, oneflag, H, BN_*RN_, DN_, DN_);
  bnl_sum_k<<<RN_*8, 256, 0, stream>>>(H, BNP);
  bnl_apply_k<<<BN_*RN_, 256, 0, stream>>>(H, vbn_lg, vbn_lb, BNP, oneflag);
  gemm_k<<<dim3(32,2), 256, 0, stream>>>(IMG_AVE, 1, vg_w, 0, vg_b, 1, 0, oneflag, G, BN_, DN_, DN_);
  bn_global_k<<<4, 256, 0, stream>>>(G, vbn_gg, vbn_gb, oneflag);
  wraw_k<<<BN_*RN_, 256, 0, stream>>>(H, G, vc_w, vc_b, WRAW, oneflag);
  glo_k<<<BN_, 256, 0, stream>>>(WRAW, img, IMG_GLO, RNORM, oneflag);
  partial_k<<<BN_*RN_, 256, 0, stream>>>(WRAW, adjs, img, RNORM, IMG_PARH, oneflag);

  // ---- caption pipeline ----
  gemm_nt_mfma_k<<<dim3(16,20), 256, 0, stream>>>(cap, (const void*)0, 0, WT_TL,
      tsa_lb, 1, 1, oneflag, LE, CN_*WN_, DN_, DN_);
  gemm_k<<<dim3(32,1), 256, 0, stream>>>(CAP_AVE, 1, tsa_gw, 0, tsa_gb, 1, 1, oneflag, GE, CN_, DN_, DN_);
  capglo_k<<<CN_, 256, 0, stream>>>(LE, GE, tsa_cw, tsa_cb, cap, CAP_GLO, oneflag);
  // ATTNR aliases H/LE — both dead by here
  gemm_nt_mfma_k<<<dim3(36,20), 256, 0, stream>>>(cap, img, 1, (const u16*)0,
      (const void*)0, 0, 0, oneflag, ATTNR, CN_*WN_, BN_*RN_, DN_);
  attn_norm_k<<<CN_*WN_, 256, 0, stream>>>(ATTNR);

  // ---- similarity heads ----
  simglo_k<<<CN_*BN_, 256, 0, stream>>>(IMG_GLO, CAP_GLO, glo_w, glo_b, SIMGLO, out, oneflag);
  wts_mfma_k<<<CN_*BN_*RN_/64, 256, 0, stream>>>(IMG_PARH, CAP_GLO, WT_PAR, par_b, SIMGLO, sim_w, sim_b, WTSR, oneflag);
  ln_k<<<8, 256, 0, stream>>>(WTSR, ln_g, ln_b, WTSF, oneflag);
  simloc_mfma_k<<<CN_*BN_*RN_/64, 256, 0, stream>>>(ATTNR, cap, img, WT_LOC, loc_b, WTSF, GRAM, out, oneflag);
}

// Round 7
// 1733.935 us; speedup vs baseline: 1.4146x; 1.1136x over previous
//
#include <hip/hip_runtime.h>

typedef unsigned short u16;
typedef __attribute__((ext_vector_type(8))) short short8;
typedef __attribute__((ext_vector_type(4))) float f32x4;

#define BN_ 64
#define CN_ 32
#define WN_ 40
#define RN_ 36
#define DN_ 1024
#define SN_ 256
#define KN_ 5
#define EPS_ 1e-8f
#define BNE_ 1e-5f
#define LNE_ 1e-5f
#define SMOOTH_ 9.0f

__device__ __forceinline__ float bf2f(u16 u){ return __uint_as_float(((unsigned)u)<<16); }
__device__ __forceinline__ u16 f2bf(float f){
  unsigned u = __float_as_uint(f);
  u += 0x7fffu + ((u>>16)&1u);
  return (u16)(u>>16);
}
// mode=1: tensors are float32. mode=0: bf16 (confirmed mode==0 on this harness)
__device__ __forceinline__ float ldf(const void* p, size_t i, int mode){
  return mode ? ((const float*)p)[i] : bf2f(((const u16*)p)[i]);
}
__device__ __forceinline__ void stf(void* p, size_t i, float v, int mode){
  if (mode) ((float*)p)[i] = v; else ((u16*)p)[i] = f2bf(v);
}
__device__ __forceinline__ int get_mode(const unsigned* oneflag){
  return (oneflag[0] == 0x3F800000u) ? 1 : 0;   // ln_g[0]==1.0f as f32
}
__device__ __forceinline__ short8 ld_frag8(const void* p, size_t elem, int mode){
  if (mode == 0){
    union { uint4 u; short8 s; } cv;
    cv.u = *(const uint4*)((const u16*)p + elem);
    return cv.s;
  } else {
    const float* f = (const float*)p;
    short8 r;
#pragma unroll
    for (int j=0;j<8;j++) r[j] = (short)f2bf(f[elem+j]);
    return r;
  }
}
// load 4 consecutive elements as floats
__device__ __forceinline__ void ld4f(const void* p, size_t off, int mode, float* o){
  if (mode==0){
    uint2 v = *(const uint2*)((const u16*)p + off);
    o[0]=bf2f((u16)(v.x&0xffffu)); o[1]=bf2f((u16)(v.x>>16));
    o[2]=bf2f((u16)(v.y&0xffffu)); o[3]=bf2f((u16)(v.y>>16));
  } else {
    const float* f=(const float*)p + off;
#pragma unroll
    for (int j=0;j<4;j++) o[j]=f[j];
  }
}

__device__ __forceinline__ float wave_sum(float v){
#pragma unroll
  for (int off=32; off>0; off>>=1) v += __shfl_down(v, off, 64);
  return v;
}
// blockDim.x == 256
__device__ float block_sum(float v, float* sc4){
  v = wave_sum(v);
  if ((threadIdx.x & 63)==0) sc4[threadIdx.x>>6] = v;
  __syncthreads();
  float r = sc4[0]+sc4[1]+sc4[2]+sc4[3];
  __syncthreads();
  return r;
}

// ---------------- mean over middle axis
__global__ void mean_k(const void* X, float* out, int G, int L, float inv, const unsigned* oneflag){
  int mode = get_mode(oneflag);
  int idx = blockIdx.x*256 + threadIdx.x;
  if (idx >= G*DN_) return;
  int g = idx >> 10, d = idx & 1023;
  size_t base = (size_t)g*L*DN_ + d;
  float s = 0.f;
  for (int l=0; l<L; l++) s += ldf(X, base + (size_t)l*DN_, mode);
  out[idx] = s*inv;
}

// ---------------- retile weight W (K=1024, N cols) -> WT[kt][n][64] bf16
__global__ void prep_w_k(const void* W, u16* WT, int nlog2, const unsigned* oneflag){
  int mode = get_mode(oneflag);
  int N = 1 << nlog2;
  int idx = blockIdx.x*256 + threadIdx.x;
  if (idx >= (DN_<<nlog2)) return;
  int k = idx >> nlog2, n = idx & (N-1);
  float v = ldf(W, idx, mode);
  WT[(((size_t)(k>>6))*N + n)*64 + (k&63)] = f2bf(v);
}

// ---------------- retile caption: cap[c][word][k] -> capTG[c][kt][kelem 64][word 40] bf16
__global__ void prep_capt_k(const void* cap, u16* capTG, const unsigned* oneflag){
  __shared__ u16 tile[WN_][72];
  int mode = get_mode(oneflag);
  int blk = blockIdx.x; int c = blk>>4, kt = blk&15;
  int t = threadIdx.x;
  if (mode==0){
    for (int i=t; i<WN_*8; i+=256){
      int wd=i>>3, ch=i&7;
      uint4 v = *(const uint4*)((const u16*)cap + ((size_t)(c*WN_+wd)*DN_ + kt*64 + ch*8));
      *(uint4*)&tile[wd][ch*8] = v;
    }
  } else {
    for (int i=t; i<WN_*64; i+=256){
      int wd=i>>6, e=i&63;
      tile[wd][e] = f2bf(((const float*)cap)[(size_t)(c*WN_+wd)*DN_ + kt*64 + e]);
    }
  }
  __syncthreads();
  for (int i=t; i<64*WN_; i+=256){
    int kelem=i/WN_, wd=i-kelem*WN_;
    capTG[((size_t)(c*16+kt)*64 + kelem)*WN_ + wd] = tile[wd][kelem];
  }
}

// ================= generic MFMA NT-GEMM (zero LDS / zero barriers) =================
__global__ __launch_bounds__(256) void gemm_nt_mfma_k(
    const void* A, const void* B, int bt, const u16* WT,
    const void* bias, int has_bias, int act, const unsigned* oneflag,
    float* C, int M, int N, int K){
  int mode = get_mode(oneflag);
  int t = threadIdx.x;
  int w = t>>6, lane = t&63, q = lane>>4, cm = lane&15;
  int m0 = blockIdx.y*64, n0 = blockIdx.x*64 + w*16;
  f32x4 acc[4];
#pragma unroll
  for (int mt=0;mt<4;mt++) acc[mt] = (f32x4){0.f,0.f,0.f,0.f};
  int nkt = K>>6;
  for (int kt=0; kt<nkt; kt++){
#pragma unroll
    for (int ks=0; ks<2; ks++){
      int kb = kt*64 + ks*32 + q*8;
      short8 b;
      if (bt) b = ld_frag8(B, (size_t)(n0+cm)*K + kb, mode);
      else {
        union { uint4 u; short8 s; } cv;
        cv.u = *(const uint4*)(WT + (((size_t)kt*N + n0+cm)*64 + ks*32 + q*8));
        b = cv.s;
      }
#pragma unroll
      for (int mt=0; mt<4; mt++){
        short8 a = ld_frag8(A, (size_t)(m0+mt*16+cm)*K + kb, mode);
        acc[mt] = __builtin_amdgcn_mfma_f32_16x16x32_bf16(a, b, acc[mt], 0,0,0);
      }
    }
  }
  float bv = has_bias ? ldf(bias, n0+cm, mode) : 0.f;
#pragma unroll
  for (int mt=0; mt<4; mt++){
#pragma unroll
    for (int r=0; r<4; r++){
      int m = m0 + mt*16 + q*4 + r;
      float v = acc[mt][r] + bv;
      if (act==1) v = tanhf(v);
      C[(size_t)m*N + n0+cm] = v;
    }
  }
}

// ---------------- BN-local split
__global__ void bnl_sum_k(const float* h, float* bnp){
  __shared__ float sc[4];
  int r = blockIdx.x>>3, bg = blockIdx.x&7;
  float s=0.f, s2=0.f;
  for (int bb=0; bb<8; bb++){
    int b = bg*8+bb;
    const float* p = h + ((size_t)b*RN_ + r)*DN_;
    for (int d=threadIdx.x; d<DN_; d+=256){ float x=p[d]; s+=x; s2+=x*x; }
  }
  s  = block_sum(s,  sc);
  s2 = block_sum(s2, sc);
  if (threadIdx.x==0){ bnp[blockIdx.x*2]=s; bnp[blockIdx.x*2+1]=s2; }
}
__global__ void bnl_apply_k(float* h, const void* gg_, const void* bb_,
                            const float* bnp, const unsigned* oneflag){
  int mode = get_mode(oneflag);
  int row = blockIdx.x; int r = row % RN_;
  float s=0.f, s2=0.f;
  for (int j=0;j<8;j++){ s += bnp[(r*8+j)*2]; s2 += bnp[(r*8+j)*2+1]; }
  float inv = 1.f/(float)(BN_*DN_);
  float mu = s*inv;
  float var = s2*inv - mu*mu;
  float rstd = rsqrtf(var + BNE_);
  float gg = ldf(gg_, r, mode), bb = ldf(bb_, r, mode);
  float* p = h + (size_t)row*DN_;
  for (int d=threadIdx.x; d<DN_; d+=256) p[d] = tanhf((p[d]-mu)*rstd*gg + bb);
}

// ---------------- BN over batch per feature + tanh
__global__ void bn_global_k(float* g, const void* gg_, const void* bb_, const unsigned* oneflag){
  int mode = get_mode(oneflag);
  int d = blockIdx.x*256 + threadIdx.x;
  if (d >= DN_) return;
  float s=0.f, s2=0.f;
  for (int b=0;b<BN_;b++){ float x=g[(size_t)b*DN_+d]; s+=x; s2+=x*x; }
  float m = s/(float)BN_;
  float var = s2/(float)BN_ - m*m;
  float rstd = rsqrtf(var + BNE_);
  float ga=ldf(gg_,d,mode), be=ldf(bb_,d,mode);
  for (int b=0;b<BN_;b++){
    size_t i=(size_t)b*DN_+d;
    g[i] = tanhf((g[i]-m)*rstd*ga + be);
  }
}

// ---------------- VALU tiled GEMM (two tiny f32-A GEMMs)
__global__ void gemm_k(const void* A, int a_ws, const void* B, int transb,
                       const void* bias, int has_bias, int act,
                       const unsigned* oneflag, float* C, int M, int N, int K){
  __shared__ float As[32][33];
  __shared__ float Bs[32][33];
  int mode = get_mode(oneflag);
  int n0 = blockIdx.x*32, m0 = blockIdx.y*32;
  int tid = threadIdx.x;
  int tx = tid & 15, ty = tid >> 4;
  float a00=0,a01=0,a10=0,a11=0;
  for (int kt=0; kt<K; kt+=32){
    for (int l=0; l<4; l++){
      int idx = tid + l*256;
      {
        int i = idx >> 5, k = idx & 31;
        int m = m0 + i;
        float v = 0.f;
        if (m < M){
          size_t off = (size_t)m*K + kt + k;
          v = a_ws ? ((const float*)A)[off] : ldf(A, off, mode);
        }
        As[i][k] = v;
      }
      if (!transb){
        int k = idx >> 5, j = idx & 31;
        int n = n0 + j;
        Bs[k][j] = (n<N) ? ldf(B, (size_t)(kt+k)*N + n, mode) : 0.f;
      } else {
        int j = idx >> 5, k = idx & 31;
        int n = n0 + j;
        Bs[k][j] = (n<N) ? ldf(B, (size_t)n*K + kt + k, mode) : 0.f;
      }
    }
    __syncthreads();
#pragma unroll
    for (int kk=0; kk<32; kk++){
      float x0 = As[ty][kk], x1 = As[ty+16][kk];
      float y0 = Bs[kk][tx], y1 = Bs[kk][tx+16];
      a00 += x0*y0; a01 += x0*y1; a10 += x1*y0; a11 += x1*y1;
    }
    __syncthreads();
  }
  float acc[2][2] = {{a00,a01},{a10,a11}};
  for (int i=0;i<2;i++){
    for (int j=0;j<2;j++){
      int m = m0 + ty + i*16, n = n0 + tx + j*16;
      if (m<M && n<N){
        float v = acc[i][j];
        if (has_bias) v += ldf(bias, n, mode);
        if (act==1) v = tanhf(v);
        C[(size_t)m*N + n] = v;
      }
    }
  }
}

// ---------------- weights_raw[b,r]
__global__ void wraw_k(const float* lemb, const float* gemb, const void* vc_w, const void* vc_b,
                       float* wraw, const unsigned* oneflag){
  __shared__ float sc[4];
  int mode = get_mode(oneflag);
  int br = blockIdx.x; int b = br / RN_;
  const float* lp = lemb + (size_t)br*DN_;
  const float* gp = gemb + (size_t)b*DN_;
  float s=0.f;
  for (int d=threadIdx.x; d<DN_; d+=256) s += lp[d]*gp[d]*ldf(vc_w,d,mode);
  s = block_sum(s, sc);
  if (threadIdx.x==0) wraw[br] = s + ldf(vc_b,0,mode);
}

// ---------------- region softmax -> weighted sum -> l2norm
__global__ void glo_k(const float* wraw, const void* img, float* img_glo, float* rnorm,
                      const unsigned* oneflag){
  __shared__ float sc[4];
  __shared__ float wsm[RN_];
  __shared__ float srn;
  int mode = get_mode(oneflag);
  int b = blockIdx.x;
  if (threadIdx.x==0){
    float mx=-1e30f;
    for (int r=0;r<RN_;r++) mx = fmaxf(mx, wraw[b*RN_+r]);
    float sum=0.f;
    for (int r=0;r<RN_;r++){ float e=expf(wraw[b*RN_+r]-mx); wsm[r]=e; sum+=e; }
    float inv=1.f/sum;
    for (int r=0;r<RN_;r++) wsm[r]*=inv;
  }
  __syncthreads();
  float ng[4]; float s2=0.f;
#pragma unroll
  for (int j=0;j<4;j++){
    int d = threadIdx.x + j*256;
    float s=0.f;
    for (int r=0;r<RN_;r++) s += wsm[r]*ldf(img, ((size_t)b*RN_+r)*DN_ + d, mode);
    ng[j]=s; s2 += s*s;
  }
  s2 = block_sum(s2, sc);
  if (threadIdx.x==0) srn = 1.f/(sqrtf(s2)+EPS_);
  __syncthreads();
  float rn = srn;
#pragma unroll
  for (int j=0;j<4;j++) img_glo[(size_t)b*DN_ + threadIdx.x + j*256] = ng[j]*rn;
  if (threadIdx.x==0) rnorm[b]=rn;
}

// ---------------- partial embeddings (output bf16)
__global__ void partial_k(const float* wraw, const int* adjs, const void* img,
                          const float* rnorm, u16* img_parh, const unsigned* oneflag){
  __shared__ float wg[KN_];
  __shared__ int eff[KN_];
  int mode = get_mode(oneflag);
  int br = blockIdx.x; int b = br / RN_; int r = br % RN_;
  if (threadIdx.x==0){
    int cnt=0;
    const int* ap = adjs + (size_t)br*RN_;
    for (int j=0;j<RN_ && cnt<KN_;j++) if (ap[j]==1) eff[cnt++]=j;
    for (int k=cnt;k<KN_;k++) eff[k]=r;
    float v[KN_]; float mx=-1e30f;
    for (int k=0;k<KN_;k++){ v[k]=wraw[b*RN_+eff[k]]; mx=fmaxf(mx,v[k]); }
    float sum=0.f;
    for (int k=0;k<KN_;k++){ v[k]=expf(v[k]-mx); sum+=v[k]; }
    float inv=1.f/sum;
    for (int k=0;k<KN_;k++) wg[k]=v[k]*inv;
  }
  __syncthreads();
  float rn = rnorm[b];
  for (int d=threadIdx.x; d<DN_; d+=256){
    float s=0.f;
#pragma unroll
    for (int k=0;k<KN_;k++) s += wg[k]*ldf(img, ((size_t)b*RN_+eff[k])*DN_ + d, mode);
    img_parh[(size_t)br*DN_ + d] = f2bf(s*rn);
  }
}

// ---------------- caption attention pool -> cap_glo (f32 + bf16 copies)
__global__ void capglo_k(const float* le, const float* ge, const void* tsa_cw, const void* tsa_cb,
                         const void* cap, float* cap_glo, u16* cap_glo_h, const unsigned* oneflag){
  __shared__ float sc[4];
  __shared__ float score[WN_];
  __shared__ float srn;
  int mode = get_mode(oneflag);
  int c = blockIdx.x;
  int t = threadIdx.x;
  float gw[4];
#pragma unroll
  for (int j=0;j<4;j++){ int d=t+j*256; gw[j] = ge[(size_t)c*DN_+d]*ldf(tsa_cw,d,mode); }
  float cb0 = ldf(tsa_cb,0,mode);
  for (int n=0;n<WN_;n++){
    const float* lp = le + ((size_t)c*WN_+n)*DN_;
    float s=0.f;
#pragma unroll
    for (int j=0;j<4;j++) s += lp[t+j*256]*gw[j];
    s = block_sum(s, sc);
    if (t==0) score[n] = s + cb0;
  }
  __syncthreads();
  if (t==0){
    float mx=-1e30f;
    for (int n=0;n<WN_;n++) mx=fmaxf(mx,score[n]);
    float sum=0.f;
    for (int n=0;n<WN_;n++){ float e=expf(score[n]-mx); score[n]=e; sum+=e; }
    float inv=1.f/sum;
    for (int n=0;n<WN_;n++) score[n]*=inv;
  }
  __syncthreads();
  float v[4]; float s2=0.f;
#pragma unroll
  for (int j=0;j<4;j++){
    int d=t+j*256;
    float s=0.f;
    for (int n=0;n<WN_;n++) s += score[n]*ldf(cap, ((size_t)c*WN_+n)*DN_ + d, mode);
    v[j]=s; s2+=s*s;
  }
  s2 = block_sum(s2, sc);
  if (t==0) srn = 1.f/(sqrtf(s2)+EPS_);
  __syncthreads();
#pragma unroll
  for (int j=0;j<4;j++){
    float o = v[j]*srn;
    cap_glo[(size_t)c*DN_ + t + j*256] = o;
    cap_glo_h[(size_t)c*DN_ + t + j*256] = f2bf(o);
  }
}

// ---------------- leaky_relu + l2norm over region segments; block per (c,n) row
__global__ void attn_norm_k(float* attn){
  __shared__ float buf[BN_*RN_];
  int row = blockIdx.x;           // c*WN_+n
  int t = threadIdx.x;
  float* p = attn + (size_t)row*(BN_*RN_);
  for (int i=t; i<BN_*RN_; i+=256){
    float x = p[i];
    buf[i] = (x>=0.f)? x : 0.1f*x;
  }
  __syncthreads();
  if (t < BN_){
    float s2=0.f;
#pragma unroll
    for (int r=0;r<RN_;r++){ float x=buf[t*RN_+r]; s2+=x*x; }
    float rn = 1.f/(sqrtf(s2)+EPS_);
#pragma unroll
    for (int r=0;r<RN_;r++) buf[t*RN_+r] *= rn;
  }
  __syncthreads();
  for (int i=t; i<BN_*RN_; i+=256) p[i] = buf[i];
}

// ---------------- per-caption Gram
__global__ void gram_k(const void* cap, float* gram, const unsigned* oneflag){
  __shared__ float capS[WN_][128];
  int mode = get_mode(oneflag);
  int c = blockIdx.x, t = threadIdx.x;
  float acc[7];
  int pi[7], pj[7];
#pragma unroll
  for (int u=0; u<7; u++){
    acc[u]=0.f;
    int p = t + u*256;
    pi[u] = p/40; pj[u] = p%40;
    if (pi[u] >= WN_) pi[u] = 0;
  }
  for (int k0=0; k0<DN_; k0+=128){
    for (int i=t; i<WN_*128; i+=256){
      int n = i>>7, kk = i&127;
      capS[n][kk] = ldf(cap, ((size_t)c*WN_+n)*DN_ + k0+kk, mode);
    }
    __syncthreads();
#pragma unroll
    for (int u=0; u<7; u++){
      if (t + u*256 < 1600){
        float s=0.f;
        for (int kk=0; kk<128; kk++) s += capS[pi[u]][kk]*capS[pj[u]][kk];
        acc[u] += s;
      }
    }
    __syncthreads();
  }
#pragma unroll
  for (int u=0; u<7; u++)
    if (t + u*256 < 1600) gram[(size_t)c*1600 + t + u*256] = acc[u];
}

// ---------------- sim_glo
__global__ void simglo_k(const float* img_glo, const float* cap_glo, const void* glo_w,
                         const void* glo_b, float* simglo_ws, void* out, const unsigned* oneflag){
  __shared__ float X[DN_];
  __shared__ float sc[4];
  __shared__ float srn;
  int mode = get_mode(oneflag);
  int cb = blockIdx.x; int c = cb >> 6; int b = cb & 63;
  int t = threadIdx.x;
#pragma unroll
  for (int j=0;j<4;j++){
    int d=t+j*256;
    float dif = img_glo[(size_t)b*DN_+d] - cap_glo[(size_t)c*DN_+d];
    X[d] = dif*dif;
  }
  __syncthreads();
  float acc=0.f;
  for (int k=0;k<DN_;k++) acc += X[k]*ldf(glo_w, (size_t)k*SN_ + t, mode);
  acc += ldf(glo_b, t, mode);
  acc = fmaxf(acc, 0.f);
  float s2 = block_sum(acc*acc, sc);
  if (t==0) srn = 1.f/(sqrtf(s2)+EPS_);
  __syncthreads();
  float o = acc*srn;
  simglo_ws[(size_t)cb*SN_ + t] = o;
  stf(out, (size_t)cb*37*SN_ + t, o, mode);
  stf(out, (size_t)CN_*BN_*37*SN_ + (size_t)cb*SN_ + t, o, mode);
}

// ---- fused sim_par -> wts_raw
__global__ __launch_bounds__(256) void wts_mfma_k(const u16* img_parh, const u16* cap_glo_h,
    const u16* WT, const void* par_b, const float* simglo, const void* sim_w,
    const void* sim_b, float* wts_raw, const unsigned* oneflag){
  __shared__ uint4 AsV[2][512];
  __shared__ float red[4][64];
  __shared__ float rns[64];
  int mode = get_mode(oneflag);
  int t = threadIdx.x;
  int rows0 = blockIdx.x*64;
  int c = rows0 / (BN_*RN_);
  int br0 = rows0 % (BN_*RN_);
  int w = t>>6, lane = t&63, q = lane>>4, cm = lane&15;
  f32x4 acc[4][4];
#pragma unroll
  for (int mt=0;mt<4;mt++)
#pragma unroll
    for (int nt=0;nt<4;nt++) acc[mt][nt] = (f32x4){0.f,0.f,0.f,0.f};

  for (int kt=0; kt<16; kt++){
    int p = kt&1;
#pragma unroll
    for (int h=0; h<2; h++){
      int fi = t + h*256;
      int mt = fi>>7, ks=(fi>>6)&1, ln=fi&63;
      int fq = ln>>4, fcm = ln&15;
      int row = mt*16+fcm;
      int kb = kt*64 + ks*32 + fq*8;
      union { uint4 u; u16 s[8]; } pv, cv, xs;
      pv.u = *(const uint4*)(img_parh + (size_t)(br0+row)*DN_ + kb);
      cv.u = *(const uint4*)(cap_glo_h + (size_t)c*DN_ + kb);
#pragma unroll
      for (int j=0;j<8;j++){ float d = bf2f(pv.s[j]) - bf2f(cv.s[j]); xs.s[j] = f2bf(d*d); }
      AsV[p][fi & 511] = xs.u;
    }
    __syncthreads();
#pragma unroll
    for (int ks=0; ks<2; ks++){
      short8 a[4];
#pragma unroll
      for (int mt=0; mt<4; mt++){
        union { uint4 u; short8 s; } cv;
        cv.u = AsV[p][(mt*2+ks)*64 + lane];
        a[mt] = cv.s;
      }
#pragma unroll
      for (int nt=0; nt<4; nt++){
        int n = w*64 + nt*16 + cm;
        union { uint4 u; short8 s; } bv;
        bv.u = *(const uint4*)(WT + (((size_t)kt*SN_ + n)*64 + ks*32 + q*8));
#pragma unroll
        for (int mt=0; mt<4; mt++)
          acc[mt][nt] = __builtin_amdgcn_mfma_f32_16x16x32_bf16(a[mt], bv.s, acc[mt][nt], 0,0,0);
      }
    }
  }
  int sarr[4]; float sw[4];
#pragma unroll
  for (int nt=0; nt<4; nt++){
    int s = w*64+nt*16+cm;
    sarr[nt] = s;
    float pb = ldf(par_b, s, mode);
    sw[nt] = ldf(sim_w, s, mode);
#pragma unroll
    for (int mt=0;mt<4;mt++)
#pragma unroll
      for (int r=0;r<4;r++) acc[mt][nt][r] = fmaxf(acc[mt][nt][r]+pb, 0.f);
  }
#pragma unroll
  for (int mt=0;mt<4;mt++)
#pragma unroll
  for (int r=0;r<4;r++){
    float v=0.f;
#pragma unroll
    for (int nt=0;nt<4;nt++) v += acc[mt][nt][r]*acc[mt][nt][r];
    v += __shfl_xor(v,1,64); v += __shfl_xor(v,2,64);
    v += __shfl_xor(v,4,64); v += __shfl_xor(v,8,64);
    if (cm==0) red[w][mt*16+q*4+r] = v;
  }
  __syncthreads();
  if (t<64) rns[t] = 1.f/(sqrtf(red[0][t]+red[1][t]+red[2][t]+red[3][t])+EPS_);
  __syncthreads();
#pragma unroll
  for (int mt=0;mt<4;mt++)
#pragma unroll
  for (int r=0;r<4;r++){
    int rowl = mt*16+q*4+r;
    int br = br0+rowl; int b = br/RN_; int cb = c*BN_+b;
    float v=0.f;
#pragma unroll
    for (int nt=0;nt<4;nt++) v += acc[mt][nt][r]*simglo[(size_t)cb*SN_+sarr[nt]]*sw[nt];
    v += __shfl_xor(v,1,64); v += __shfl_xor(v,2,64);
    v += __shfl_xor(v,4,64); v += __shfl_xor(v,8,64);
    if (cm==0) red[w][rowl] = v;
  }
  __syncthreads();
  if (t<64) wts_raw[rows0+t] = (red[0][t]+red[1][t]+red[2][t]+red[3][t])*rns[t] + ldf(sim_b,0,mode);
}

// ---------------- LN over regions + sigmoid
__global__ void ln_k(const float* wts_raw, const void* ln_g, const void* ln_b,
                     float* wts_f, const unsigned* oneflag){
  int mode = get_mode(oneflag);
  int cb = blockIdx.x*256 + threadIdx.x;
  if (cb >= CN_*BN_) return;
  const float* p = wts_raw + (size_t)cb*RN_;
  float s=0.f, s2=0.f;
#pragma unroll
  for (int r=0;r<RN_;r++){ float x=p[r]; s+=x; s2+=x*x; }
  float m = s/(float)RN_;
  float v = s2/(float)RN_ - m*m;
  float rstd = rsqrtf(v + LNE_);
  float* q = wts_f + (size_t)cb*RN_;
#pragma unroll
  for (int r=0;r<RN_;r++){
    float x = (p[r]-m)*rstd*ldf(ln_g,r,mode) + ldf(ln_b,r,mode);
    q[r] = 1.f/(1.f+expf(-x));
  }
}

// ---- fused simloc v3: ctx via MFMA (D[kelem][row], Pt preloaded in regs),
//      double-buffered capT/Xs, 1 barrier/kt, manually aliased LDS.
#define SM_CAPT   0          // u16 [2][64][72] = 18432 B (loop; aliases A40s+Gc in preamble)
#define SM_XS     18432      // u16 [2][64][72] = 18432 B
#define SM_A40    0          // f32 [64][41] = 10496 B (preamble)
#define SM_GC     10496      // f32 [1600]   =  6400 B (preamble)
#define SM_PST    36864      // u16 [64][72] = 9216 B (persist)
#define SM_CRN    46080      // f32 [64]
#define SM_RED    46336      // f32 [4][64]
#define SM_RNS    47360      // f32 [64]
#define SM_TOTAL  47616

__global__ __launch_bounds__(256) void simloc_mfma_k(const float* attnr, const u16* capTG,
    const void* img, const u16* WT, const void* loc_b, const float* wts_f,
    const float* gram, void* out, const unsigned* oneflag){
  __shared__ char smem[SM_TOTAL];
  u16*   capT = (u16*)(smem + SM_CAPT);
  u16*   Xs   = (u16*)(smem + SM_XS);
  float* A40  = (float*)(smem + SM_A40);
  float* Gc   = (float*)(smem + SM_GC);
  u16*   PsT  = (u16*)(smem + SM_PST);
  float* crn  = (float*)(smem + SM_CRN);
  float* red  = (float*)(smem + SM_RED);
  float* rns  = (float*)(smem + SM_RNS);

  int mode = get_mode(oneflag);
  int t = threadIdx.x;
  int rows0 = blockIdx.x*64;
  int c = rows0 / (BN_*RN_);
  int br0 = rows0 % (BN_*RN_);
  int w = t>>6, lane = t&63, q = lane>>4, cm = lane&15;

  // ---- preamble: attention rows + Gram into (aliased) LDS
  for (int i=t; i<64*WN_; i+=256){
    int rr = i&63, n = i>>6;
    A40[rr*41+n] = attnr[((size_t)c*WN_+n)*(BN_*RN_) + br0 + rr];
  }
  for (int i=t; i<WN_*WN_; i+=256) Gc[i] = gram[(size_t)c*1600 + i];
  __syncthreads();
  // softmax per row; emit PsT[word][row] bf16 with zero pad rows 40..63
  if (t < 64){
    float mx=-1e30f;
#pragma unroll
    for (int n=0;n<WN_;n++) mx = fmaxf(mx, A40[t*41+n]);
    float sum=0.f;
    float e[WN_];
#pragma unroll
    for (int n=0;n<WN_;n++){ e[n]=expf(SMOOTH_*(A40[t*41+n]-mx)); sum+=e[n]; }
    float inv=1.f/sum;
#pragma unroll
    for (int n=0;n<WN_;n++){ float pv=e[n]*inv; A40[t*41+n]=pv; PsT[n*72+t]=f2bf(pv); }
#pragma unroll
    for (int n=WN_;n<64;n++) PsT[n*72+t]=0;
  }
  __syncthreads();
  {  // ||ctx_row||^2 = p^T G p, 4 threads per row
    int row = t>>2, pp = t&3;
    float gs = 0.f;
    for (int i=0;i<WN_;i++){
      float ai = A40[row*41+i];
      float ps = 0.f;
      for (int j=pp; j<WN_; j+=4) ps += A40[row*41+j]*Gc[i*WN_+j];
      gs += ai*ps;
    }
    gs += __shfl_xor(gs,1,64); gs += __shfl_xor(gs,2,64);
    if (pp==0) crn[row] = 1.f/(sqrtf(fmaxf(gs,0.f))+EPS_);
  }
  __syncthreads();   // preamble reads (A40/Gc) complete before loop region reuse

  // preload PsT B-fragments (kt-invariant): B[k=word][n=row], row group = w*16
  short8 bP[2];
#pragma unroll
  for (int ks2=0; ks2<2; ks2++)
#pragma unroll
    for (int j=0;j<8;j++) bP[ks2][j] = (short)PsT[(ks2*32+q*8+j)*72 + w*16+cm];

  // zero capT word-pads (40..63) both buffers; stage capT[0] for kt=0
  for (int i=t; i<2*64*24; i+=256){
    int buf = i/1536, rem = i - buf*1536;
    int kelem = rem/24, wd = 40 + rem - (rem/24)*24;
    capT[((size_t)(buf*64+kelem))*72 + wd] = 0;
  }
  for (int i=t; i<320; i+=256){
    int kelem = i/5, wc = i - kelem*5;
    uint4 v = *(const uint4*)(capTG + (((size_t)(c*16+0)*64 + kelem)*WN_ + wc*8));
    *(uint4*)(capT + (size_t)kelem*72 + wc*8) = v;
  }
  float cr = 0.f;   // crn for this lane's row
  {
    cr = crn[w*16+cm];
  }

  f32x4 acc[4][4];
#pragma unroll
  for (int mt=0;mt<4;mt++)
#pragma unroll
    for (int nt=0;nt<4;nt++) acc[mt][nt] = (f32x4){0.f,0.f,0.f,0.f};
  __syncthreads();

  for (int kt=0; kt<16; kt++){
    int p = kt&1;
    // stage next capT slab (overlaps with compute below)
    if (kt < 15){
      int pn = p^1;
      for (int i=t; i<320; i+=256){
        int kelem = i/5, wc = i - kelem*5;
        uint4 v = *(const uint4*)(capTG + (((size_t)(c*16+kt+1)*64 + kelem)*WN_ + wc*8));
        *(uint4*)(capT + ((size_t)(pn*64+kelem))*72 + wc*8) = v;
      }
    }
    // ctx MFMA: D[kelem][row] = capT[kelem][word] @ PsT[word][row]
    f32x4 ctxacc[4];
#pragma unroll
    for (int mt2=0;mt2<4;mt2++) ctxacc[mt2] = (f32x4){0.f,0.f,0.f,0.f};
#pragma unroll
    for (int ks2=0; ks2<2; ks2++){
#pragma unroll
      for (int mt2=0; mt2<4; mt2++){
        union { uint4 u; short8 s; } av;
        av.u = *(const uint4*)(capT + ((size_t)(p*64+mt2*16+cm))*72 + ks2*32 + q*8);
        ctxacc[mt2] = __builtin_amdgcn_mfma_f32_16x16x32_bf16(av.s, bP[ks2], ctxacc[mt2], 0,0,0);
      }
    }
    // X formation: lane owns row w*16+cm, kelems mt2*16+q*4..+3 -> 8B vector writes
    int rowg = w*16+cm;
#pragma unroll
    for (int mt2=0; mt2<4; mt2++){
      float iv[4];
      ld4f(img, (size_t)(br0+rowg)*DN_ + kt*64 + mt2*16 + q*4, mode, iv);
      u16 xa[4];
#pragma unroll
      for (int r=0;r<4;r++){
        float x = ctxacc[mt2][r]*cr - iv[r];
        xa[r] = f2bf(x*x);
      }
      uint2 pk;
      pk.x = (unsigned)xa[0] | ((unsigned)xa[1]<<16);
      pk.y = (unsigned)xa[2] | ((unsigned)xa[3]<<16);
      *(uint2*)(Xs + ((size_t)(p*64+rowg))*72 + mt2*16 + q*4) = pk;
    }
    __syncthreads();
    // main MFMA from Xs + WT
#pragma unroll
    for (int ks=0; ks<2; ks++){
      short8 a[4];
#pragma unroll
      for (int mt=0; mt<4; mt++){
        union { uint4 u; short8 s; } av;
        av.u = *(const uint4*)(Xs + ((size_t)(p*64+mt*16+cm))*72 + ks*32 + q*8);
        a[mt] = av.s;
      }
#pragma unroll
      for (int nt=0; nt<4; nt++){
        int n = w*64 + nt*16 + cm;
        union { uint4 u; short8 s; } bv;
        bv.u = *(const uint4*)(WT + (((size_t)kt*SN_ + n)*64 + ks*32 + q*8));
#pragma unroll
        for (int mt=0; mt<4; mt++)
          acc[mt][nt] = __builtin_amdgcn_mfma_f32_16x16x32_bf16(a[mt], bv.s, acc[mt][nt], 0,0,0);
      }
    }
  }
  // epilogue: bias + relu, row l2norm, scale, store
  int sarr[4];
#pragma unroll
  for (int nt=0; nt<4; nt++){
    int s = w*64+nt*16+cm;
    sarr[nt] = s;
    float lb = ldf(loc_b, s, mode);
#pragma unroll
    for (int mt=0;mt<4;mt++)
#pragma unroll
      for (int r=0;r<4;r++) acc[mt][nt][r] = fmaxf(acc[mt][nt][r]+lb, 0.f);
  }
#pragma unroll
  for (int mt=0;mt<4;mt++)
#pragma unroll
  for (int r=0;r<4;r++){
    float v=0.f;
#pragma unroll
    for (int nt=0;nt<4;nt++) v += acc[mt][nt][r]*acc[mt][nt][r];
    v += __shfl_xor(v,1,64); v += __shfl_xor(v,2,64);
    v += __shfl_xor(v,4,64); v += __shfl_xor(v,8,64);
    if (cm==0) red[w*64 + mt*16+q*4+r] = v;
  }
  __syncthreads();
  if (t<64) rns[t] = 1.f/(sqrtf(red[t]+red[64+t]+red[128+t]+red[192+t])+EPS_);
  __syncthreads();
#pragma unroll
  for (int mt=0;mt<4;mt++)
#pragma unroll
  for (int r=0;r<4;r++){
    int rowl = mt*16+q*4+r;
    int br = br0+rowl; int b = br/RN_; int rr = br%RN_; int cb = c*BN_+b;
    float scl = rns[rowl]*wts_f[rows0+rowl];
    size_t obase = ((size_t)(cb*37) + 1 + rr)*SN_;
#pragma unroll
    for (int nt=0;nt<4;nt++) stf(out, obase + sarr[nt], acc[mt][nt][r]*scl, mode);
  }
}

extern "C" void kernel_launch(void* const* d_in, const int* in_sizes, int n_in,
                              void* d_out, int out_size, void* d_ws, size_t ws_size,
                              hipStream_t stream) {
  const void* img    = d_in[0];
  const void* cap    = d_in[1];
  const int*  adjs   = (const int*)d_in[3];
  const void* tsa_lw = d_in[5];
  const void* tsa_lb = d_in[6];
  const void* tsa_gw = d_in[7];
  const void* tsa_gb = d_in[8];
  const void* tsa_cw = d_in[9];
  const void* tsa_cb = d_in[10];
  const void* vl_w   = d_in[11];
  const void* vl_b   = d_in[12];
  const void* vbn_lg = d_in[13];
  const void* vbn_lb = d_in[14];
  const void* vg_w   = d_in[15];
  const void* vg_b   = d_in[16];
  const void* vbn_gg = d_in[17];
  const void* vbn_gb = d_in[18];
  const void* vc_w   = d_in[19];
  const void* vc_b   = d_in[20];
  const void* loc_w  = d_in[21];
  const void* loc_b  = d_in[22];
  const void* par_w  = d_in[23];
  const void* par_b  = d_in[24];
  const void* glo_w  = d_in[25];
  const void* glo_b  = d_in[26];
  const void* sim_w  = d_in[27];
  const void* sim_b  = d_in[28];
  const void* ln_g   = d_in[29];
  const void* ln_b   = d_in[30];
  const unsigned* oneflag = (const unsigned*)d_in[29];  // ln_g == ones: dtype probe
  void* out = d_out;

  // ---- workspace layout (float units), ~28.8 MB ----
  float* f = (float*)d_ws;
  float* U        = f;                      // 3,670,016 floats, multi-use:
  float* H        = U;                      //   2304*1024 (dead after wraw_k)
  float* LE       = U + 2359296;            //   1280*1024 (dead after capglo_k)
  float* ATTNR    = U;                      //   1280*2304 (after H+LE dead)
  float* CAPTGf   = U + 2949120;            //   1,310,720 u16 = 655,360 floats (after LE dead)
  float* IMG_PARHf= U        + 3670016;     // 2304*1024 u16 = 1179648 floats
  float* IMG_AVE  = IMG_PARHf+ 1179648;     // 64*1024
  float* G        = IMG_AVE  + 65536;       // 64*1024
  float* WRAW     = G        + 65536;       // 2304
  float* RNORM    = WRAW     + 2304;        // 64
  float* IMG_GLO  = RNORM    + 64;          // 64*1024
  float* CAP_AVE  = IMG_GLO  + 65536;       // 32*1024
  float* GE       = CAP_AVE  + 32768;       // 32*1024
  float* CAP_GLO  = GE       + 32768;       // 32*1024
  float* SIMGLO   = CAP_GLO  + 32768;       // 32*64*256
  float* WTSR     = SIMGLO   + 524288;      // 32*64*36
  float* WTSF     = WTSR     + 73728;       // 32*64*36
  float* WTLOCf   = WTSF     + 73728;       // 1024*256 u16 = 131072 floats
  float* WTPARf   = WTLOCf   + 131072;      // 131072
  float* WTVLf    = WTPARf   + 131072;      // 1024*1024 u16 = 524288 floats
  float* WTTLf    = WTVLf    + 524288;      // 524288
  float* GRAM     = WTTLf    + 524288;      // 32*1600
  float* BNP      = GRAM     + 51200;       // 576
  float* CAPGLOHf = BNP      + 576;         // 32*1024 u16 = 16384 floats
  u16* IMG_PARH = (u16*)IMG_PARHf;
  u16* WT_LOC = (u16*)WTLOCf;
  u16* WT_PAR = (u16*)WTPARf;
  u16* WT_VL  = (u16*)WTVLf;
  u16* WT_TL  = (u16*)WTTLf;
  u16* CAPTG  = (u16*)CAPTGf;
  u16* CAPGLOH= (u16*)CAPGLOHf;

  // ---- prep: retiled weights + caption Grams ----
  prep_w_k<<<1024, 256, 0, stream>>>(loc_w, WT_LOC, 8, oneflag);
  prep_w_k<<<1024, 256, 0, stream>>>(par_w, WT_PAR, 8, oneflag);
  prep_w_k<<<4096, 256, 0, stream>>>(vl_w,  WT_VL, 10, oneflag);
  prep_w_k<<<4096, 256, 0, stream>>>(tsa_lw,WT_TL, 10, oneflag);
  gram_k<<<CN_, 256, 0, stream>>>(cap, GRAM, oneflag);

  // ---- caption-independent image pipeline ----
  mean_k<<<256, 256, 0, stream>>>(img, IMG_AVE, BN_, RN_, 1.f/RN_, oneflag);
  mean_k<<<128, 256, 0, stream>>>(cap, CAP_AVE, CN_, WN_, 1.f/WN_, oneflag);
  gemm_nt_mfma_k<<<dim3(16,36), 256, 0, stream>>>(img, (const void*)0, 0, WT_VL,
      vl_b, 1, 0, oneflag, H, BN_*RN_, DN_, DN_);
  bnl_sum_k<<<RN_*8, 256, 0, stream>>>(H, BNP);
  bnl_apply_k<<<BN_*RN_, 256, 0, stream>>>(H, vbn_lg, vbn_lb, BNP, oneflag);
  gemm_k<<<dim3(32,2), 256, 0, stream>>>(IMG_AVE, 1, vg_w, 0, vg_b, 1, 0, oneflag, G, BN_, DN_, DN_);
  bn_global_k<<<4, 256, 0, stream>>>(G, vbn_gg, vbn_gb, oneflag);
  wraw_k<<<BN_*RN_, 256, 0, stream>>>(H, G, vc_w, vc_b, WRAW, oneflag);
  glo_k<<<BN_, 256, 0, stream>>>(WRAW, img, IMG_GLO, RNORM, oneflag);
  partial_k<<<BN_*RN_, 256, 0, stream>>>(WRAW, adjs, img, RNORM, IMG_PARH, oneflag);

  // ---- caption pipeline ----
  gemm_nt_mfma_k<<<dim3(16,20), 256, 0, stream>>>(cap, (const void*)0, 0, WT_TL,
      tsa_lb, 1, 1, oneflag, LE, CN_*WN_, DN_, DN_);
  gemm_k<<<dim3(32,1), 256, 0, stream>>>(CAP_AVE, 1, tsa_gw, 0, tsa_gb, 1, 1, oneflag, GE, CN_, DN_, DN_);
  capglo_k<<<CN_, 256, 0, stream>>>(LE, GE, tsa_cw, tsa_cb, cap, CAP_GLO, CAPGLOH, oneflag);
  // LE dead: CAPTG + ATTNR may now use U
  prep_capt_k<<<CN_*16, 256, 0, stream>>>(cap, CAPTG, oneflag);
  gemm_nt_mfma_k<<<dim3(36,20), 256, 0, stream>>>(cap, img, 1, (const u16*)0,
      (const void*)0, 0, 0, oneflag, ATTNR, CN_*WN_, BN_*RN_, DN_);
  attn_norm_k<<<CN_*WN_, 256, 0, stream>>>(ATTNR);

  // ---- similarity heads ----
  simglo_k<<<CN_*BN_, 256, 0, stream>>>(IMG_GLO, CAP_GLO, glo_w, glo_b, SIMGLO, out, oneflag);
  wts_mfma_k<<<CN_*BN_*RN_/64, 256, 0, stream>>>(IMG_PARH, CAPGLOH, WT_PAR, par_b, SIMGLO, sim_w, sim_b, WTSR, oneflag);
  ln_k<<<8, 256, 0, stream>>>(WTSR, ln_g, ln_b, WTSF, oneflag);
  simloc_mfma_k<<<CN_*BN_*RN_/64, 256, 0, stream>>>(ATTNR, CAPTG, img, WT_LOC, loc_b, WTSF, GRAM, out, oneflag);
}